// Round 1
// baseline (2160.986 us; speedup 1.0000x reference)
//
#include <hip/hip_runtime.h>

// GNN link predict: 2-layer GAT (H=2, C=64, HC=128) + factored MLP decoder.
// All fp32. Softmax max-subtraction skipped (alpha invariant to m; logits bounded).

// ---------------- GEMM: Y[nrows,128] = X[nrows,128] @ W[128,128] ----------------
// W staged in LDS (64KB); 16-row chunks of X staged (8KB); thread = 2 rows x 4 cols.
__global__ __launch_bounds__(256) void gemm128(
    const float* __restrict__ X, const float* __restrict__ W,
    float* __restrict__ Y, int nrows)
{
    __shared__ float Wl[128 * 128];
    __shared__ float Xl[16 * 128];
    const int t = threadIdx.x;
    for (int i = t * 4; i < 128 * 128; i += 256 * 4)
        *reinterpret_cast<float4*>(&Wl[i]) = *reinterpret_cast<const float4*>(&W[i]);

    const int rg = t >> 5;          // 0..7 (row pair group)
    const int c0 = (t & 31) * 4;    // column group

    for (int base = blockIdx.x * 16; base < nrows; base += gridDim.x * 16) {
        const int nh = min(16, nrows - base);
        __syncthreads();  // protects Xl reuse; first iteration also fences W staging
        {
            const int idx = t * 8;  // 2048 floats / 256 threads
            if ((idx >> 7) < nh) {
                *reinterpret_cast<float4*>(&Xl[idx]) =
                    *reinterpret_cast<const float4*>(&X[(size_t)base * 128 + idx]);
                *reinterpret_cast<float4*>(&Xl[idx + 4]) =
                    *reinterpret_cast<const float4*>(&X[(size_t)base * 128 + idx + 4]);
            }
        }
        __syncthreads();

        const int r0 = 2 * rg, r1 = 2 * rg + 1;
        if (r1 < nh) {
            float a0 = 0.f, a1 = 0.f, a2 = 0.f, a3 = 0.f;
            float b0 = 0.f, b1 = 0.f, b2 = 0.f, b3 = 0.f;
#pragma unroll 8
            for (int k = 0; k < 128; ++k) {
                const float4 wv = *reinterpret_cast<const float4*>(&Wl[k * 128 + c0]);
                const float x0 = Xl[r0 * 128 + k];
                const float x1 = Xl[r1 * 128 + k];
                a0 = fmaf(x0, wv.x, a0); a1 = fmaf(x0, wv.y, a1);
                a2 = fmaf(x0, wv.z, a2); a3 = fmaf(x0, wv.w, a3);
                b0 = fmaf(x1, wv.x, b0); b1 = fmaf(x1, wv.y, b1);
                b2 = fmaf(x1, wv.z, b2); b3 = fmaf(x1, wv.w, b3);
            }
            *reinterpret_cast<float4*>(&Y[(size_t)(base + r0) * 128 + c0]) = make_float4(a0, a1, a2, a3);
            *reinterpret_cast<float4*>(&Y[(size_t)(base + r1) * 128 + c0]) = make_float4(b0, b1, b2, b3);
        } else {
            for (int r = r0; r <= r1; ++r) {
                if (r < nh) {
                    float a0 = 0.f, a1 = 0.f, a2 = 0.f, a3 = 0.f;
                    for (int k = 0; k < 128; ++k) {
                        const float4 wv = *reinterpret_cast<const float4*>(&Wl[k * 128 + c0]);
                        const float xv = Xl[r * 128 + k];
                        a0 = fmaf(xv, wv.x, a0); a1 = fmaf(xv, wv.y, a1);
                        a2 = fmaf(xv, wv.z, a2); a3 = fmaf(xv, wv.w, a3);
                    }
                    *reinterpret_cast<float4*>(&Y[(size_t)(base + r) * 128 + c0]) = make_float4(a0, a1, a2, a3);
                }
            }
        }
    }
}

// ---------------- attention coefficients: one wave per node ----------------
// a_s[n,h] = dot(h[n,h,:], att_src[h,:]); a_d likewise.
__global__ __launch_bounds__(256) void attn_coef(
    const float* __restrict__ h, const float* __restrict__ att_s,
    const float* __restrict__ att_d, float2* __restrict__ as_out,
    float2* __restrict__ ad_out, int n)
{
    const int wid = (blockIdx.x * blockDim.x + threadIdx.x) >> 6;
    const int lane = threadIdx.x & 63;
    if (wid >= n) return;
    const float* hr = h + (size_t)wid * 128;
    const float h0 = hr[lane];        // head 0, c = lane
    const float h1 = hr[64 + lane];   // head 1, c = lane
    float s0 = h0 * att_s[lane];
    float s1 = h1 * att_s[64 + lane];
    float d0 = h0 * att_d[lane];
    float d1 = h1 * att_d[64 + lane];
#pragma unroll
    for (int off = 32; off; off >>= 1) {
        s0 += __shfl_xor(s0, off, 64);
        s1 += __shfl_xor(s1, off, 64);
        d0 += __shfl_xor(d0, off, 64);
        d1 += __shfl_xor(d1, off, 64);
    }
    if (lane == 0) {
        as_out[wid] = make_float2(s0, s1);
        ad_out[wid] = make_float2(d0, d1);
    }
}

// ---------------- softmax denominators: thread per edge ----------------
__global__ __launch_bounds__(256) void edge_denom(
    const int* __restrict__ esrc, const int* __restrict__ edst, int E_, int Etot,
    const float2* __restrict__ as_, const float2* __restrict__ ad_,
    float* __restrict__ den)
{
    const int e = blockIdx.x * blockDim.x + threadIdx.x;
    if (e >= Etot) return;
    int s, d;
    if (e < E_) { s = esrc[e]; d = edst[e]; } else { s = d = e - E_; }
    const float2 A = as_[s], B = ad_[d];
    float e0 = A.x + B.x; e0 = e0 > 0.f ? e0 : 0.2f * e0;
    float e1 = A.y + B.y; e1 = e1 > 0.f ? e1 : 0.2f * e1;
    atomicAdd(&den[2 * d],     expf(e0));
    atomicAdd(&den[2 * d + 1], expf(e1));
}

// ---------------- aggregation: 128 threads per edge, atomic scatter ----------------
__global__ __launch_bounds__(256) void edge_aggregate(
    const int* __restrict__ esrc, const int* __restrict__ edst, int E_, int Etot,
    const float* __restrict__ h, const float2* __restrict__ as_,
    const float2* __restrict__ ad_, const float2* __restrict__ den,
    float* __restrict__ agg)
{
    const long long tot = (long long)Etot * 128;
    const long long stride = (long long)gridDim.x * blockDim.x;
    for (long long gid = (long long)blockIdx.x * blockDim.x + threadIdx.x;
         gid < tot; gid += stride) {
        const int e = (int)(gid >> 7);
        const int c = (int)(gid & 127);
        int s, d;
        if (e < E_) { s = esrc[e]; d = edst[e]; } else { s = d = e - E_; }
        const int hd = c >> 6;
        const float2 A = as_[s], B = ad_[d], Dn = den[d];
        float ev = hd ? (A.y + B.y) : (A.x + B.x);
        ev = ev > 0.f ? ev : 0.2f * ev;
        const float alpha = expf(ev) / (hd ? Dn.y : Dn.x);
        atomicAdd(&agg[(size_t)d * 128 + c], h[(size_t)s * 128 + c] * alpha);
    }
}

// ---------------- finalize: out = (relu?)(agg + bias) ----------------
__global__ __launch_bounds__(256) void finalize_k(
    const float* __restrict__ agg, const float* __restrict__ bias,
    float* __restrict__ out, int total, int do_relu)
{
    const int stride = gridDim.x * blockDim.x;
    for (int i = blockIdx.x * blockDim.x + threadIdx.x; i < total; i += stride) {
        float v = agg[i] + bias[i & 127];
        if (do_relu) v = v > 0.f ? v : 0.f;
        out[i] = v;
    }
}

// ---------------- build rearranged decoder weight: Wuv[128][128] ----------------
// Wuv[k][j] = lin1_w[k][j] (j<64)  |  lin1_w[128+k][j-64] (j>=64); lin1_w is (256,64).
__global__ void build_wuv(const float* __restrict__ lin1_w, float* __restrict__ Wuv)
{
    const int i = blockIdx.x * blockDim.x + threadIdx.x;
    if (i >= 128 * 128) return;
    const int k = i >> 7, j = i & 127;
    Wuv[i] = (j < 64) ? lin1_w[k * 64 + j] : lin1_w[(128 + k) * 64 + (j - 64)];
}

// ---------------- decoder: one wave per label edge ----------------
__global__ __launch_bounds__(256) void decode_k(
    const int* __restrict__ eli, int L_, const float* __restrict__ uv,
    const float* __restrict__ lin1_b, const float* __restrict__ lin2_w,
    const float* __restrict__ lin2_b, float* __restrict__ out)
{
    const int lane = threadIdx.x & 63;
    const int wstride = (gridDim.x * blockDim.x) >> 6;
    for (int wid = (blockIdx.x * blockDim.x + threadIdx.x) >> 6; wid < L_; wid += wstride) {
        const int a = eli[wid], b = eli[L_ + wid];
        float x = uv[(size_t)a * 128 + lane] + uv[(size_t)b * 128 + 64 + lane] + lin1_b[lane];
        x = x > 0.f ? x : 0.f;
        float p = x * lin2_w[lane];
#pragma unroll
        for (int off = 32; off; off >>= 1) p += __shfl_xor(p, off, 64);
        if (lane == 0) out[wid] = p + lin2_b[0];
    }
}

extern "C" void kernel_launch(void* const* d_in, const int* in_sizes, int n_in,
                              void* d_out, int out_size, void* d_ws, size_t ws_size,
                              hipStream_t stream)
{
    const float* x     = (const float*)d_in[0];
    const int*   ei    = (const int*)d_in[1];
    const int*   eli   = (const int*)d_in[2];
    const float* W1    = (const float*)d_in[3];
    const float* atts1 = (const float*)d_in[4];
    const float* attd1 = (const float*)d_in[5];
    const float* bias1 = (const float*)d_in[6];
    const float* W2    = (const float*)d_in[7];
    const float* atts2 = (const float*)d_in[8];
    const float* attd2 = (const float*)d_in[9];
    const float* bias2 = (const float*)d_in[10];
    const float* lin1w = (const float*)d_in[11];
    const float* lin1b = (const float*)d_in[12];
    const float* lin2w = (const float*)d_in[13];
    const float* lin2b = (const float*)d_in[14];
    float* out = (float*)d_out;

    const int N = in_sizes[0] / 128;
    const int E = in_sizes[1] / 2;
    const int L = in_sizes[2] / 2;
    const int Etot = E + N;

    float* ws  = (float*)d_ws;
    float* h   = ws;                       // N*128  (h1, h2, then uv)
    float* agg = h   + (size_t)N * 128;    // N*128
    float* x2z = agg + (size_t)N * 128;    // N*128  (x2 after layer1, z after layer2)
    float* a_s = x2z + (size_t)N * 128;    // N*2
    float* a_d = a_s + (size_t)N * 2;      // N*2
    float* den = a_d + (size_t)N * 2;      // N*2
    float* Wuv = den + (size_t)N * 2;      // 128*128

    const int GEMM_GRID   = 1250;
    const int attnBlocks  = (N + 3) / 4;          // 4 waves/block
    const int denomBlocks = (Etot + 255) / 256;

    for (int layer = 0; layer < 2; ++layer) {
        const float* xin  = (layer == 0) ? x : x2z;
        const float* W    = (layer == 0) ? W1 : W2;
        const float* as_w = (layer == 0) ? atts1 : atts2;
        const float* ad_w = (layer == 0) ? attd1 : attd2;
        const float* bs   = (layer == 0) ? bias1 : bias2;

        gemm128<<<GEMM_GRID, 256, 0, stream>>>(xin, W, h, N);
        attn_coef<<<attnBlocks, 256, 0, stream>>>(h, as_w, ad_w,
                                                  (float2*)a_s, (float2*)a_d, N);
        hipMemsetAsync(den, 0, (size_t)N * 2 * sizeof(float), stream);
        edge_denom<<<denomBlocks, 256, 0, stream>>>(ei, ei + E, E, Etot,
                                                    (const float2*)a_s, (const float2*)a_d, den);
        hipMemsetAsync(agg, 0, (size_t)N * 128 * sizeof(float), stream);
        edge_aggregate<<<32768, 256, 0, stream>>>(ei, ei + E, E, Etot, h,
                                                  (const float2*)a_s, (const float2*)a_d,
                                                  (const float2*)den, agg);
        finalize_k<<<4096, 256, 0, stream>>>(agg, bs, x2z, N * 128, (layer == 0) ? 1 : 0);
    }

    build_wuv<<<64, 256, 0, stream>>>(lin1w, Wuv);
    gemm128<<<GEMM_GRID, 256, 0, stream>>>(x2z, Wuv, h, N);   // h := uv [N,128]
    decode_k<<<8192, 256, 0, stream>>>(eli, L, h, lin1b, lin2w, lin2b, out);
}

// Round 2
// 1392.790 us; speedup vs baseline: 1.5516x; 1.5516x over previous
//
#include <hip/hip_runtime.h>

// GNN link predict: 2-layer GAT (H=2, C=64, HC=128) + factored MLP decoder.
// All fp32. Softmax max-subtraction skipped (alpha invariant to m; logits bounded).
// Aggregation via on-device CSR (built once) -> register-accumulate -> single write.

// ---------------- GEMM: Y[nrows,128] = X[nrows,128] @ W[128,128] ----------------
__global__ __launch_bounds__(256) void gemm128(
    const float* __restrict__ X, const float* __restrict__ W,
    float* __restrict__ Y, int nrows)
{
    __shared__ float Wl[128 * 128];
    __shared__ float Xl[16 * 128];
    const int t = threadIdx.x;
    for (int i = t * 4; i < 128 * 128; i += 256 * 4)
        *reinterpret_cast<float4*>(&Wl[i]) = *reinterpret_cast<const float4*>(&W[i]);

    const int rg = t >> 5;          // 0..7 (row pair group)
    const int c0 = (t & 31) * 4;    // column group

    for (int base = blockIdx.x * 16; base < nrows; base += gridDim.x * 16) {
        const int nh = min(16, nrows - base);
        __syncthreads();
        {
            const int idx = t * 8;
            if ((idx >> 7) < nh) {
                *reinterpret_cast<float4*>(&Xl[idx]) =
                    *reinterpret_cast<const float4*>(&X[(size_t)base * 128 + idx]);
                *reinterpret_cast<float4*>(&Xl[idx + 4]) =
                    *reinterpret_cast<const float4*>(&X[(size_t)base * 128 + idx + 4]);
            }
        }
        __syncthreads();

        const int r0 = 2 * rg, r1 = 2 * rg + 1;
        if (r1 < nh) {
            float a0 = 0.f, a1 = 0.f, a2 = 0.f, a3 = 0.f;
            float b0 = 0.f, b1 = 0.f, b2 = 0.f, b3 = 0.f;
#pragma unroll 8
            for (int k = 0; k < 128; ++k) {
                const float4 wv = *reinterpret_cast<const float4*>(&Wl[k * 128 + c0]);
                const float x0 = Xl[r0 * 128 + k];
                const float x1 = Xl[r1 * 128 + k];
                a0 = fmaf(x0, wv.x, a0); a1 = fmaf(x0, wv.y, a1);
                a2 = fmaf(x0, wv.z, a2); a3 = fmaf(x0, wv.w, a3);
                b0 = fmaf(x1, wv.x, b0); b1 = fmaf(x1, wv.y, b1);
                b2 = fmaf(x1, wv.z, b2); b3 = fmaf(x1, wv.w, b3);
            }
            *reinterpret_cast<float4*>(&Y[(size_t)(base + r0) * 128 + c0]) = make_float4(a0, a1, a2, a3);
            *reinterpret_cast<float4*>(&Y[(size_t)(base + r1) * 128 + c0]) = make_float4(b0, b1, b2, b3);
        } else {
            for (int r = r0; r <= r1; ++r) {
                if (r < nh) {
                    float a0 = 0.f, a1 = 0.f, a2 = 0.f, a3 = 0.f;
                    for (int k = 0; k < 128; ++k) {
                        const float4 wv = *reinterpret_cast<const float4*>(&Wl[k * 128 + c0]);
                        const float xv = Xl[r * 128 + k];
                        a0 = fmaf(xv, wv.x, a0); a1 = fmaf(xv, wv.y, a1);
                        a2 = fmaf(xv, wv.z, a2); a3 = fmaf(xv, wv.w, a3);
                    }
                    *reinterpret_cast<float4*>(&Y[(size_t)(base + r) * 128 + c0]) = make_float4(a0, a1, a2, a3);
                }
            }
        }
    }
}

// ---------------- attention coefficients: one wave per node ----------------
__global__ __launch_bounds__(256) void attn_coef(
    const float* __restrict__ h, const float* __restrict__ att_s,
    const float* __restrict__ att_d, float2* __restrict__ as_out,
    float2* __restrict__ ad_out, int n)
{
    const int wid = (blockIdx.x * blockDim.x + threadIdx.x) >> 6;
    const int lane = threadIdx.x & 63;
    if (wid >= n) return;
    const float* hr = h + (size_t)wid * 128;
    const float h0 = hr[lane];
    const float h1 = hr[64 + lane];
    float s0 = h0 * att_s[lane];
    float s1 = h1 * att_s[64 + lane];
    float d0 = h0 * att_d[lane];
    float d1 = h1 * att_d[64 + lane];
#pragma unroll
    for (int off = 32; off; off >>= 1) {
        s0 += __shfl_xor(s0, off, 64);
        s1 += __shfl_xor(s1, off, 64);
        d0 += __shfl_xor(d0, off, 64);
        d1 += __shfl_xor(d1, off, 64);
    }
    if (lane == 0) {
        as_out[wid] = make_float2(s0, s1);
        ad_out[wid] = make_float2(d0, d1);
    }
}

// ---------------- CSR build ----------------
__global__ __launch_bounds__(256) void init_counts_k(int* __restrict__ counts, int N)
{
    const int i = blockIdx.x * blockDim.x + threadIdx.x;
    if (i < N) counts[i] = 1;   // self-loop pre-counted
}

__global__ __launch_bounds__(256) void hist_k(
    const int* __restrict__ edst, int E, int* __restrict__ counts)
{
    const int stride = gridDim.x * blockDim.x;
    for (int e = blockIdx.x * blockDim.x + threadIdx.x; e < E; e += stride)
        atomicAdd(&counts[edst[e]], 1);
}

// single-block exclusive scan: row_ptr[0..N], each thread owns a contiguous run
__global__ __launch_bounds__(1024) void scan_k(
    const int* __restrict__ counts, int* __restrict__ row_ptr, int N)
{
    __shared__ int part[1024];
    const int t = threadIdx.x;
    const int chunk = (N + 1023) / 1024;
    const int lo = t * chunk, hi = min(lo + chunk, N);
    int s = 0;
    for (int i = lo; i < hi; ++i) s += counts[i];
    part[t] = s;
    __syncthreads();
    for (int off = 1; off < 1024; off <<= 1) {
        int v = (t >= off) ? part[t - off] : 0;
        __syncthreads();
        part[t] += v;
        __syncthreads();
    }
    int base = (t == 0) ? 0 : part[t - 1];
    for (int i = lo; i < hi; ++i) { row_ptr[i] = base; base += counts[i]; }
    if (t == 1023) row_ptr[N] = part[1023];
}

// cursor[n] = row_ptr[n]+1; self-loop gets deterministic slot 0 of each segment
__global__ __launch_bounds__(256) void init_cursor_k(
    const int* __restrict__ row_ptr, int* __restrict__ cursor,
    int* __restrict__ csr_src, int N)
{
    const int i = blockIdx.x * blockDim.x + threadIdx.x;
    if (i < N) {
        const int p = row_ptr[i];
        csr_src[p] = i;
        cursor[i] = p + 1;
    }
}

__global__ __launch_bounds__(256) void scatter_k(
    const int* __restrict__ esrc, const int* __restrict__ edst, int E,
    int* __restrict__ cursor, int* __restrict__ csr_src)
{
    const int stride = gridDim.x * blockDim.x;
    for (int e = blockIdx.x * blockDim.x + threadIdx.x; e < E; e += stride) {
        const int pos = atomicAdd(&cursor[edst[e]], 1);
        csr_src[pos] = esrc[e];
    }
}

// ---------------- CSR aggregation: 128 threads per node ----------------
// phase 1: softmax denominator (lane-parallel over in-edges);
// phase 2: serial edge loop, channel-parallel fma; single write with bias(+relu).
__global__ __launch_bounds__(256) void csr_aggregate(
    const int* __restrict__ row_ptr, const int* __restrict__ csr_src,
    const float* __restrict__ h, const float2* __restrict__ as_,
    const float2* __restrict__ ad_, const float* __restrict__ bias,
    float* __restrict__ out, int N, int do_relu)
{
    __shared__ float red[2][2][2];   // [group][wave-in-group][head]
    const int grp  = threadIdx.x >> 7;          // 0..1
    const int c    = threadIdx.x & 127;         // channel
    const int node = blockIdx.x * 2 + grp;
    const bool valid = node < N;

    int start = 0, end = 0;
    float2 ad = make_float2(0.f, 0.f);
    if (valid) {
        start = row_ptr[node];
        end   = row_ptr[node + 1];
        ad    = ad_[node];
    }

    // phase 1: denominators
    float den0 = 0.f, den1 = 0.f;
    for (int i = start + c; i < end; i += 128) {
        const float2 as = as_[csr_src[i]];
        float e0 = as.x + ad.x; e0 = e0 > 0.f ? e0 : 0.2f * e0;
        float e1 = as.y + ad.y; e1 = e1 > 0.f ? e1 : 0.2f * e1;
        den0 += expf(e0);
        den1 += expf(e1);
    }
#pragma unroll
    for (int off = 32; off; off >>= 1) {
        den0 += __shfl_xor(den0, off, 64);
        den1 += __shfl_xor(den1, off, 64);
    }
    const int wv = (threadIdx.x >> 6) & 1;
    if ((threadIdx.x & 63) == 0) { red[grp][wv][0] = den0; red[grp][wv][1] = den1; }
    __syncthreads();
    den0 = red[grp][0][0] + red[grp][1][0];
    den1 = red[grp][0][1] + red[grp][1][1];

    // phase 2: aggregate
    if (valid) {
        const float rden = 1.f / ((c >> 6) ? den1 : den0);
        const float adh  = (c >> 6) ? ad.y : ad.x;
        float acc = 0.f;
        for (int i = start; i < end; ++i) {
            const int s = csr_src[i];
            const float2 as = as_[s];
            float ev = ((c >> 6) ? as.y : as.x) + adh;
            ev = ev > 0.f ? ev : 0.2f * ev;
            const float alpha = expf(ev) * rden;
            acc = fmaf(alpha, h[(size_t)s * 128 + c], acc);
        }
        float v = acc + bias[c];
        if (do_relu) v = v > 0.f ? v : 0.f;
        out[(size_t)node * 128 + c] = v;
    }
}

// ---------------- build rearranged decoder weight: Wuv[128][128] ----------------
__global__ void build_wuv(const float* __restrict__ lin1_w, float* __restrict__ Wuv)
{
    const int i = blockIdx.x * blockDim.x + threadIdx.x;
    if (i >= 128 * 128) return;
    const int k = i >> 7, j = i & 127;
    Wuv[i] = (j < 64) ? lin1_w[k * 64 + j] : lin1_w[(128 + k) * 64 + (j - 64)];
}

// ---------------- decoder: one wave per label edge ----------------
__global__ __launch_bounds__(256) void decode_k(
    const int* __restrict__ eli, int L_, const float* __restrict__ uv,
    const float* __restrict__ lin1_b, const float* __restrict__ lin2_w,
    const float* __restrict__ lin2_b, float* __restrict__ out)
{
    const int lane = threadIdx.x & 63;
    const int wstride = (gridDim.x * blockDim.x) >> 6;
    for (int wid = (blockIdx.x * blockDim.x + threadIdx.x) >> 6; wid < L_; wid += wstride) {
        const int a = eli[wid], b = eli[L_ + wid];
        float x = uv[(size_t)a * 128 + lane] + uv[(size_t)b * 128 + 64 + lane] + lin1_b[lane];
        x = x > 0.f ? x : 0.f;
        float p = x * lin2_w[lane];
#pragma unroll
        for (int off = 32; off; off >>= 1) p += __shfl_xor(p, off, 64);
        if (lane == 0) out[wid] = p + lin2_b[0];
    }
}

extern "C" void kernel_launch(void* const* d_in, const int* in_sizes, int n_in,
                              void* d_out, int out_size, void* d_ws, size_t ws_size,
                              hipStream_t stream)
{
    const float* x     = (const float*)d_in[0];
    const int*   ei    = (const int*)d_in[1];
    const int*   eli   = (const int*)d_in[2];
    const float* W1    = (const float*)d_in[3];
    const float* atts1 = (const float*)d_in[4];
    const float* attd1 = (const float*)d_in[5];
    const float* bias1 = (const float*)d_in[6];
    const float* W2    = (const float*)d_in[7];
    const float* atts2 = (const float*)d_in[8];
    const float* attd2 = (const float*)d_in[9];
    const float* bias2 = (const float*)d_in[10];
    const float* lin1w = (const float*)d_in[11];
    const float* lin1b = (const float*)d_in[12];
    const float* lin2w = (const float*)d_in[13];
    const float* lin2b = (const float*)d_in[14];
    float* out = (float*)d_out;

    const int N = in_sizes[0] / 128;
    const int E = in_sizes[1] / 2;
    const int L = in_sizes[2] / 2;
    const int Etot = E + N;

    float* ws   = (float*)d_ws;
    float* h    = ws;                        // N*128
    float* x2z  = h + (size_t)N * 128;       // N*128
    float* a_s  = x2z + (size_t)N * 128;     // N*2
    float* a_d  = a_s + (size_t)N * 2;       // N*2
    float* Wuv  = a_d + (size_t)N * 2;       // 128*128
    int* row_ptr = (int*)(Wuv + 128 * 128);  // N+1
    int* counts  = row_ptr + (N + 1);        // N
    int* cursor  = counts + N;               // N
    int* csr_src = cursor + N;               // Etot

    const int GEMM_GRID  = 1250;
    const int attnBlocks = (N + 3) / 4;
    const int nBlocks256 = (N + 255) / 256;

    // ---- CSR build (once, reused by both layers) ----
    init_counts_k<<<nBlocks256, 256, 0, stream>>>(counts, N);
    hist_k<<<2048, 256, 0, stream>>>(ei + E, E, counts);
    scan_k<<<1, 1024, 0, stream>>>(counts, row_ptr, N);
    init_cursor_k<<<nBlocks256, 256, 0, stream>>>(row_ptr, cursor, csr_src, N);
    scatter_k<<<2048, 256, 0, stream>>>(ei, ei + E, E, cursor, csr_src);

    for (int layer = 0; layer < 2; ++layer) {
        const float* xin  = (layer == 0) ? x : x2z;
        const float* W    = (layer == 0) ? W1 : W2;
        const float* as_w = (layer == 0) ? atts1 : atts2;
        const float* ad_w = (layer == 0) ? attd1 : attd2;
        const float* bs   = (layer == 0) ? bias1 : bias2;

        gemm128<<<GEMM_GRID, 256, 0, stream>>>(xin, W, h, N);
        attn_coef<<<attnBlocks, 256, 0, stream>>>(h, as_w, ad_w,
                                                  (float2*)a_s, (float2*)a_d, N);
        csr_aggregate<<<(N + 1) / 2, 256, 0, stream>>>(row_ptr, csr_src, h,
                                                       (const float2*)a_s, (const float2*)a_d,
                                                       bs, x2z, N, (layer == 0) ? 1 : 0);
    }

    build_wuv<<<64, 256, 0, stream>>>(lin1w, Wuv);
    gemm128<<<GEMM_GRID, 256, 0, stream>>>(x2z, Wuv, h, N);   // h := uv
    decode_k<<<8192, 256, 0, stream>>>(eli, L, h, lin1b, lin2w, lin2b, out);
}

// Round 3
// 950.815 us; speedup vs baseline: 2.2728x; 1.4648x over previous
//
#include <hip/hip_runtime.h>

// GNN link predict: 2-layer GAT (H=2, C=64, HC=128) + factored MLP decoder.
// All fp32. Softmax max-subtraction skipped (alpha invariant to m; logits bounded).
// Aggregation: CSR (built once) -> one wave per node, single fused pass:
//   out = (sum_i ex_i * h[s_i]) / (sum_i ex_i), scaled once at the end.

// ---------------- GEMM: Y[nrows,128] = X[nrows,128] @ W[128,128] ----------------
__global__ __launch_bounds__(256) void gemm128(
    const float* __restrict__ X, const float* __restrict__ W,
    float* __restrict__ Y, int nrows)
{
    __shared__ float Wl[128 * 128];
    __shared__ float Xl[16 * 128];
    const int t = threadIdx.x;
    for (int i = t * 4; i < 128 * 128; i += 256 * 4)
        *reinterpret_cast<float4*>(&Wl[i]) = *reinterpret_cast<const float4*>(&W[i]);

    const int rg = t >> 5;          // 0..7 (row pair group)
    const int c0 = (t & 31) * 4;    // column group

    for (int base = blockIdx.x * 16; base < nrows; base += gridDim.x * 16) {
        const int nh = min(16, nrows - base);
        __syncthreads();
        {
            const int idx = t * 8;
            if ((idx >> 7) < nh) {
                *reinterpret_cast<float4*>(&Xl[idx]) =
                    *reinterpret_cast<const float4*>(&X[(size_t)base * 128 + idx]);
                *reinterpret_cast<float4*>(&Xl[idx + 4]) =
                    *reinterpret_cast<const float4*>(&X[(size_t)base * 128 + idx + 4]);
            }
        }
        __syncthreads();

        const int r0 = 2 * rg, r1 = 2 * rg + 1;
        if (r1 < nh) {
            float a0 = 0.f, a1 = 0.f, a2 = 0.f, a3 = 0.f;
            float b0 = 0.f, b1 = 0.f, b2 = 0.f, b3 = 0.f;
#pragma unroll 8
            for (int k = 0; k < 128; ++k) {
                const float4 wv = *reinterpret_cast<const float4*>(&Wl[k * 128 + c0]);
                const float x0 = Xl[r0 * 128 + k];
                const float x1 = Xl[r1 * 128 + k];
                a0 = fmaf(x0, wv.x, a0); a1 = fmaf(x0, wv.y, a1);
                a2 = fmaf(x0, wv.z, a2); a3 = fmaf(x0, wv.w, a3);
                b0 = fmaf(x1, wv.x, b0); b1 = fmaf(x1, wv.y, b1);
                b2 = fmaf(x1, wv.z, b2); b3 = fmaf(x1, wv.w, b3);
            }
            *reinterpret_cast<float4*>(&Y[(size_t)(base + r0) * 128 + c0]) = make_float4(a0, a1, a2, a3);
            *reinterpret_cast<float4*>(&Y[(size_t)(base + r1) * 128 + c0]) = make_float4(b0, b1, b2, b3);
        } else {
            for (int r = r0; r <= r1; ++r) {
                if (r < nh) {
                    float a0 = 0.f, a1 = 0.f, a2 = 0.f, a3 = 0.f;
                    for (int k = 0; k < 128; ++k) {
                        const float4 wv = *reinterpret_cast<const float4*>(&Wl[k * 128 + c0]);
                        const float xv = Xl[r * 128 + k];
                        a0 = fmaf(xv, wv.x, a0); a1 = fmaf(xv, wv.y, a1);
                        a2 = fmaf(xv, wv.z, a2); a3 = fmaf(xv, wv.w, a3);
                    }
                    *reinterpret_cast<float4*>(&Y[(size_t)(base + r) * 128 + c0]) = make_float4(a0, a1, a2, a3);
                }
            }
        }
    }
}

// ---------------- attention coefficients: one wave per node ----------------
__global__ __launch_bounds__(256) void attn_coef(
    const float* __restrict__ h, const float* __restrict__ att_s,
    const float* __restrict__ att_d, float2* __restrict__ as_out,
    float2* __restrict__ ad_out, int n)
{
    const int wid = (blockIdx.x * blockDim.x + threadIdx.x) >> 6;
    const int lane = threadIdx.x & 63;
    if (wid >= n) return;
    const float* hr = h + (size_t)wid * 128;
    const float h0 = hr[lane];
    const float h1 = hr[64 + lane];
    float s0 = h0 * att_s[lane];
    float s1 = h1 * att_s[64 + lane];
    float d0 = h0 * att_d[lane];
    float d1 = h1 * att_d[64 + lane];
#pragma unroll
    for (int off = 32; off; off >>= 1) {
        s0 += __shfl_xor(s0, off, 64);
        s1 += __shfl_xor(s1, off, 64);
        d0 += __shfl_xor(d0, off, 64);
        d1 += __shfl_xor(d1, off, 64);
    }
    if (lane == 0) {
        as_out[wid] = make_float2(s0, s1);
        ad_out[wid] = make_float2(d0, d1);
    }
}

// ---------------- CSR build ----------------
__global__ __launch_bounds__(256) void init_counts_k(int* __restrict__ counts, int N)
{
    const int i = blockIdx.x * blockDim.x + threadIdx.x;
    if (i < N) counts[i] = 1;   // self-loop pre-counted
}

__global__ __launch_bounds__(256) void hist_k(
    const int* __restrict__ edst, int E, int* __restrict__ counts)
{
    const int stride = gridDim.x * blockDim.x;
    for (int e = blockIdx.x * blockDim.x + threadIdx.x; e < E; e += stride)
        atomicAdd(&counts[edst[e]], 1);
}

// single-block exclusive scan: row_ptr[0..N], each thread owns a contiguous run
__global__ __launch_bounds__(1024) void scan_k(
    const int* __restrict__ counts, int* __restrict__ row_ptr, int N)
{
    __shared__ int part[1024];
    const int t = threadIdx.x;
    const int chunk = (N + 1023) / 1024;
    const int lo = t * chunk, hi = min(lo + chunk, N);
    int s = 0;
    for (int i = lo; i < hi; ++i) s += counts[i];
    part[t] = s;
    __syncthreads();
    for (int off = 1; off < 1024; off <<= 1) {
        int v = (t >= off) ? part[t - off] : 0;
        __syncthreads();
        part[t] += v;
        __syncthreads();
    }
    int base = (t == 0) ? 0 : part[t - 1];
    for (int i = lo; i < hi; ++i) { row_ptr[i] = base; base += counts[i]; }
    if (t == 1023) row_ptr[N] = part[1023];
}

// cursor[n] = row_ptr[n]+1; self-loop gets deterministic slot 0 of each segment
__global__ __launch_bounds__(256) void init_cursor_k(
    const int* __restrict__ row_ptr, int* __restrict__ cursor,
    int* __restrict__ csr_src, int N)
{
    const int i = blockIdx.x * blockDim.x + threadIdx.x;
    if (i < N) {
        const int p = row_ptr[i];
        csr_src[p] = i;
        cursor[i] = p + 1;
    }
}

__global__ __launch_bounds__(256) void scatter_k(
    const int* __restrict__ esrc, const int* __restrict__ edst, int E,
    int* __restrict__ cursor, int* __restrict__ csr_src)
{
    const int stride = gridDim.x * blockDim.x;
    for (int e = blockIdx.x * blockDim.x + threadIdx.x; e < E; e += stride) {
        const int pos = atomicAdd(&cursor[edst[e]], 1);
        csr_src[pos] = esrc[e];
    }
}

// ---------------- CSR aggregation: one wave per node, single pass ----------------
// Lane owns channels {2*lane, 2*lane+1}; head = lane>>5 (wave-uniform per half).
// Per 64-edge chunk: lane computes ex for one edge; inner loop broadcasts
// (s, ex0, ex1) via shfl and does one float2 gather + 2 fma. Denominator is
// accumulated alongside; one scale at the end (no second edge pass).
__global__ __launch_bounds__(256) void csr_aggregate(
    const int* __restrict__ row_ptr, const int* __restrict__ csr_src,
    const float* __restrict__ h, const float2* __restrict__ as_,
    const float2* __restrict__ ad_, const float* __restrict__ bias,
    float* __restrict__ out, int N, int do_relu)
{
    const int lane = threadIdx.x & 63;
    const int node = (blockIdx.x * blockDim.x + threadIdx.x) >> 6;
    if (node >= N) return;

    const int start = row_ptr[node];
    const int end   = row_ptr[node + 1];
    const float2 ad = ad_[node];
    const float2* __restrict__ h2 = (const float2*)h;

    float den0 = 0.f, den1 = 0.f;
    float accx = 0.f, accy = 0.f;

    for (int base = start; base < end; base += 64) {
        const int cnt = min(64, end - base);
        float ex0 = 0.f, ex1 = 0.f;
        int s = 0;
        if (lane < cnt) {
            s = csr_src[base + lane];
            const float2 as = as_[s];
            float e0 = as.x + ad.x; e0 = fmaxf(e0, 0.2f * e0);   // leaky relu
            float e1 = as.y + ad.y; e1 = fmaxf(e1, 0.2f * e1);
            ex0 = __expf(e0); ex1 = __expf(e1);
            den0 += ex0; den1 += ex1;
        }
        for (int j = 0; j < cnt; ++j) {
            const int   sj = __shfl(s, j, 64);
            const float e0 = __shfl(ex0, j, 64);
            const float e1 = __shfl(ex1, j, 64);
            const float e  = (lane < 32) ? e0 : e1;
            const float2 hv = h2[(size_t)sj * 64 + lane];
            accx = fmaf(e, hv.x, accx);
            accy = fmaf(e, hv.y, accy);
        }
    }

#pragma unroll
    for (int off = 32; off; off >>= 1) {
        den0 += __shfl_xor(den0, off, 64);
        den1 += __shfl_xor(den1, off, 64);
    }
    const float rd = 1.f / ((lane < 32) ? den0 : den1);
    const float2 bv = ((const float2*)bias)[lane];
    float vx = fmaf(accx, rd, bv.x);
    float vy = fmaf(accy, rd, bv.y);
    if (do_relu) { vx = fmaxf(vx, 0.f); vy = fmaxf(vy, 0.f); }
    ((float2*)out)[(size_t)node * 64 + lane] = make_float2(vx, vy);
}

// ---------------- build rearranged decoder weight: Wuv[128][128] ----------------
__global__ void build_wuv(const float* __restrict__ lin1_w, float* __restrict__ Wuv)
{
    const int i = blockIdx.x * blockDim.x + threadIdx.x;
    if (i >= 128 * 128) return;
    const int k = i >> 7, j = i & 127;
    Wuv[i] = (j < 64) ? lin1_w[k * 64 + j] : lin1_w[(128 + k) * 64 + (j - 64)];
}

// ---------------- decoder: one wave per label edge ----------------
__global__ __launch_bounds__(256) void decode_k(
    const int* __restrict__ eli, int L_, const float* __restrict__ uv,
    const float* __restrict__ lin1_b, const float* __restrict__ lin2_w,
    const float* __restrict__ lin2_b, float* __restrict__ out)
{
    const int lane = threadIdx.x & 63;
    const int wstride = (gridDim.x * blockDim.x) >> 6;
    for (int wid = (blockIdx.x * blockDim.x + threadIdx.x) >> 6; wid < L_; wid += wstride) {
        const int a = eli[wid], b = eli[L_ + wid];
        float x = uv[(size_t)a * 128 + lane] + uv[(size_t)b * 128 + 64 + lane] + lin1_b[lane];
        x = x > 0.f ? x : 0.f;
        float p = x * lin2_w[lane];
#pragma unroll
        for (int off = 32; off; off >>= 1) p += __shfl_xor(p, off, 64);
        if (lane == 0) out[wid] = p + lin2_b[0];
    }
}

extern "C" void kernel_launch(void* const* d_in, const int* in_sizes, int n_in,
                              void* d_out, int out_size, void* d_ws, size_t ws_size,
                              hipStream_t stream)
{
    const float* x     = (const float*)d_in[0];
    const int*   ei    = (const int*)d_in[1];
    const int*   eli   = (const int*)d_in[2];
    const float* W1    = (const float*)d_in[3];
    const float* atts1 = (const float*)d_in[4];
    const float* attd1 = (const float*)d_in[5];
    const float* bias1 = (const float*)d_in[6];
    const float* W2    = (const float*)d_in[7];
    const float* atts2 = (const float*)d_in[8];
    const float* attd2 = (const float*)d_in[9];
    const float* bias2 = (const float*)d_in[10];
    const float* lin1w = (const float*)d_in[11];
    const float* lin1b = (const float*)d_in[12];
    const float* lin2w = (const float*)d_in[13];
    const float* lin2b = (const float*)d_in[14];
    float* out = (float*)d_out;

    const int N = in_sizes[0] / 128;
    const int E = in_sizes[1] / 2;
    const int L = in_sizes[2] / 2;

    float* ws   = (float*)d_ws;
    float* h    = ws;                        // N*128
    float* x2z  = h + (size_t)N * 128;       // N*128
    float* a_s  = x2z + (size_t)N * 128;     // N*2
    float* a_d  = a_s + (size_t)N * 2;       // N*2
    float* Wuv  = a_d + (size_t)N * 2;       // 128*128
    int* row_ptr = (int*)(Wuv + 128 * 128);  // N+1
    int* counts  = row_ptr + (N + 1);        // N
    int* cursor  = counts + N;               // N
    int* csr_src = cursor + N;               // E+N

    const int GEMM_GRID  = 1250;
    const int attnBlocks = (N + 3) / 4;
    const int nBlocks256 = (N + 255) / 256;

    // ---- CSR build (once, reused by both layers) ----
    init_counts_k<<<nBlocks256, 256, 0, stream>>>(counts, N);
    hist_k<<<2048, 256, 0, stream>>>(ei + E, E, counts);
    scan_k<<<1, 1024, 0, stream>>>(counts, row_ptr, N);
    init_cursor_k<<<nBlocks256, 256, 0, stream>>>(row_ptr, cursor, csr_src, N);
    scatter_k<<<2048, 256, 0, stream>>>(ei, ei + E, E, cursor, csr_src);

    for (int layer = 0; layer < 2; ++layer) {
        const float* xin  = (layer == 0) ? x : x2z;
        const float* W    = (layer == 0) ? W1 : W2;
        const float* as_w = (layer == 0) ? atts1 : atts2;
        const float* ad_w = (layer == 0) ? attd1 : attd2;
        const float* bs   = (layer == 0) ? bias1 : bias2;

        gemm128<<<GEMM_GRID, 256, 0, stream>>>(xin, W, h, N);
        attn_coef<<<attnBlocks, 256, 0, stream>>>(h, as_w, ad_w,
                                                  (float2*)a_s, (float2*)a_d, N);
        csr_aggregate<<<(N + 3) / 4, 256, 0, stream>>>(row_ptr, csr_src, h,
                                                       (const float2*)a_s, (const float2*)a_d,
                                                       bs, x2z, N, (layer == 0) ? 1 : 0);
    }

    build_wuv<<<64, 256, 0, stream>>>(lin1w, Wuv);
    gemm128<<<GEMM_GRID, 256, 0, stream>>>(x2z, Wuv, h, N);   // h := uv
    decode_k<<<8192, 256, 0, stream>>>(eli, L, h, lin1b, lin2w, lin2b, out);
}

// Round 4
// 791.028 us; speedup vs baseline: 2.7319x; 1.2020x over previous
//
#include <hip/hip_runtime.h>

// GNN link predict: 2-layer GAT (H=2, C=64, HC=128) + factored MLP decoder.
// All fp32. Softmax max-subtraction skipped (alpha invariant to m; logits bounded).
// Aggregation: CSR (built once) -> one wave per node, single fused pass.
// CSR row_ptr built with a 3-phase hierarchical scan (fully parallel).

// ---------------- GEMM: Y[nrows,128] = X[nrows,128] @ W[128,128] ----------------
__global__ __launch_bounds__(256) void gemm128(
    const float* __restrict__ X, const float* __restrict__ W,
    float* __restrict__ Y, int nrows)
{
    __shared__ float Wl[128 * 128];
    __shared__ float Xl[16 * 128];
    const int t = threadIdx.x;
    for (int i = t * 4; i < 128 * 128; i += 256 * 4)
        *reinterpret_cast<float4*>(&Wl[i]) = *reinterpret_cast<const float4*>(&W[i]);

    const int rg = t >> 5;          // 0..7 (row pair group)
    const int c0 = (t & 31) * 4;    // column group

    for (int base = blockIdx.x * 16; base < nrows; base += gridDim.x * 16) {
        const int nh = min(16, nrows - base);
        __syncthreads();
        {
            const int idx = t * 8;
            if ((idx >> 7) < nh) {
                *reinterpret_cast<float4*>(&Xl[idx]) =
                    *reinterpret_cast<const float4*>(&X[(size_t)base * 128 + idx]);
                *reinterpret_cast<float4*>(&Xl[idx + 4]) =
                    *reinterpret_cast<const float4*>(&X[(size_t)base * 128 + idx + 4]);
            }
        }
        __syncthreads();

        const int r0 = 2 * rg, r1 = 2 * rg + 1;
        if (r1 < nh) {
            float a0 = 0.f, a1 = 0.f, a2 = 0.f, a3 = 0.f;
            float b0 = 0.f, b1 = 0.f, b2 = 0.f, b3 = 0.f;
#pragma unroll 8
            for (int k = 0; k < 128; ++k) {
                const float4 wv = *reinterpret_cast<const float4*>(&Wl[k * 128 + c0]);
                const float x0 = Xl[r0 * 128 + k];
                const float x1 = Xl[r1 * 128 + k];
                a0 = fmaf(x0, wv.x, a0); a1 = fmaf(x0, wv.y, a1);
                a2 = fmaf(x0, wv.z, a2); a3 = fmaf(x0, wv.w, a3);
                b0 = fmaf(x1, wv.x, b0); b1 = fmaf(x1, wv.y, b1);
                b2 = fmaf(x1, wv.z, b2); b3 = fmaf(x1, wv.w, b3);
            }
            *reinterpret_cast<float4*>(&Y[(size_t)(base + r0) * 128 + c0]) = make_float4(a0, a1, a2, a3);
            *reinterpret_cast<float4*>(&Y[(size_t)(base + r1) * 128 + c0]) = make_float4(b0, b1, b2, b3);
        } else {
            for (int r = r0; r <= r1; ++r) {
                if (r < nh) {
                    float a0 = 0.f, a1 = 0.f, a2 = 0.f, a3 = 0.f;
                    for (int k = 0; k < 128; ++k) {
                        const float4 wv = *reinterpret_cast<const float4*>(&Wl[k * 128 + c0]);
                        const float xv = Xl[r * 128 + k];
                        a0 = fmaf(xv, wv.x, a0); a1 = fmaf(xv, wv.y, a1);
                        a2 = fmaf(xv, wv.z, a2); a3 = fmaf(xv, wv.w, a3);
                    }
                    *reinterpret_cast<float4*>(&Y[(size_t)(base + r) * 128 + c0]) = make_float4(a0, a1, a2, a3);
                }
            }
        }
    }
}

// ---------------- attention coefficients: one wave per node ----------------
__global__ __launch_bounds__(256) void attn_coef(
    const float* __restrict__ h, const float* __restrict__ att_s,
    const float* __restrict__ att_d, float2* __restrict__ as_out,
    float2* __restrict__ ad_out, int n)
{
    const int wid = (blockIdx.x * blockDim.x + threadIdx.x) >> 6;
    const int lane = threadIdx.x & 63;
    if (wid >= n) return;
    const float* hr = h + (size_t)wid * 128;
    const float h0 = hr[lane];
    const float h1 = hr[64 + lane];
    float s0 = h0 * att_s[lane];
    float s1 = h1 * att_s[64 + lane];
    float d0 = h0 * att_d[lane];
    float d1 = h1 * att_d[64 + lane];
#pragma unroll
    for (int off = 32; off; off >>= 1) {
        s0 += __shfl_xor(s0, off, 64);
        s1 += __shfl_xor(s1, off, 64);
        d0 += __shfl_xor(d0, off, 64);
        d1 += __shfl_xor(d1, off, 64);
    }
    if (lane == 0) {
        as_out[wid] = make_float2(s0, s1);
        ad_out[wid] = make_float2(d0, d1);
    }
}

// ---------------- CSR build ----------------
__global__ __launch_bounds__(256) void init_counts_k(int* __restrict__ counts, int N)
{
    const int i = blockIdx.x * blockDim.x + threadIdx.x;
    if (i < N) counts[i] = 1;   // self-loop pre-counted
}

__global__ __launch_bounds__(256) void hist_k(
    const int* __restrict__ edst, int E, int* __restrict__ counts)
{
    const int stride = gridDim.x * blockDim.x;
    for (int e = blockIdx.x * blockDim.x + threadIdx.x; e < E; e += stride)
        atomicAdd(&counts[edst[e]], 1);
}

// ---- 3-phase hierarchical exclusive scan over counts[0..N) -> row_ptr[0..N] ----
// chunk = 1024 elements per block (256 threads x 4).
__global__ __launch_bounds__(256) void scan_phase1(
    const int* __restrict__ counts, int* __restrict__ blockSums, int N)
{
    __shared__ int wsum[4];
    const int b = blockIdx.x, t = threadIdx.x;
    const int base = b * 1024 + t * 4;
    int s = 0;
    if (base + 3 < N) {
        const int4 c = *reinterpret_cast<const int4*>(&counts[base]);
        s = c.x + c.y + c.z + c.w;
    } else {
#pragma unroll
        for (int k = 0; k < 4; ++k) if (base + k < N) s += counts[base + k];
    }
#pragma unroll
    for (int off = 32; off; off >>= 1) s += __shfl_xor(s, off, 64);
    if ((t & 63) == 0) wsum[t >> 6] = s;
    __syncthreads();
    if (t == 0) blockSums[b] = wsum[0] + wsum[1] + wsum[2] + wsum[3];
}

// single small block: exclusive-scan blockSums[0..nb) in place; row_ptr[N] = total.
__global__ __launch_bounds__(256) void scan_phase2(
    int* __restrict__ blockSums, int nb, int* __restrict__ row_ptr, int N)
{
    __shared__ int wsum[4];
    __shared__ int carry_sh;
    const int t = threadIdx.x;
    if (t == 0) carry_sh = 0;
    __syncthreads();
    for (int base = 0; base < nb; base += 256) {
        const int i = base + t;
        const int v = (i < nb) ? blockSums[i] : 0;
        int x = v;
#pragma unroll
        for (int off = 1; off < 64; off <<= 1) {
            const int y = __shfl_up(x, off, 64);
            if ((t & 63) >= off) x += y;
        }
        if ((t & 63) == 63) wsum[t >> 6] = x;
        __syncthreads();
        int woff = 0;
        for (int w = 0; w < (t >> 6); ++w) woff += wsum[w];
        const int carry = carry_sh;
        if (i < nb) blockSums[i] = carry + woff + x - v;
        __syncthreads();
        if (t == 255) carry_sh = carry + woff + x;
        __syncthreads();
    }
    if (t == 0) row_ptr[N] = carry_sh;
}

__global__ __launch_bounds__(256) void scan_phase3(
    const int* __restrict__ counts, const int* __restrict__ blockSums,
    int* __restrict__ row_ptr, int N)
{
    __shared__ int wsum[4];
    const int b = blockIdx.x, t = threadIdx.x;
    const int base = b * 1024 + t * 4;
    int v0 = 0, v1 = 0, v2 = 0, v3 = 0;
    if (base + 3 < N) {
        const int4 c = *reinterpret_cast<const int4*>(&counts[base]);
        v0 = c.x; v1 = c.y; v2 = c.z; v3 = c.w;
    } else {
        if (base + 0 < N) v0 = counts[base + 0];
        if (base + 1 < N) v1 = counts[base + 1];
        if (base + 2 < N) v2 = counts[base + 2];
        if (base + 3 < N) v3 = counts[base + 3];
    }
    const int tsum = v0 + v1 + v2 + v3;
    int x = tsum;
#pragma unroll
    for (int off = 1; off < 64; off <<= 1) {
        const int y = __shfl_up(x, off, 64);
        if ((t & 63) >= off) x += y;
    }
    if ((t & 63) == 63) wsum[t >> 6] = x;
    __syncthreads();
    int woff = 0;
    for (int w = 0; w < (t >> 6); ++w) woff += wsum[w];
    int excl = blockSums[b] + woff + x - tsum;
    if (base + 0 < N) row_ptr[base + 0] = excl;
    if (base + 1 < N) row_ptr[base + 1] = excl + v0;
    if (base + 2 < N) row_ptr[base + 2] = excl + v0 + v1;
    if (base + 3 < N) row_ptr[base + 3] = excl + v0 + v1 + v2;
}

// cursor[n] = row_ptr[n]+1; self-loop gets deterministic slot 0 of each segment
__global__ __launch_bounds__(256) void init_cursor_k(
    const int* __restrict__ row_ptr, int* __restrict__ cursor,
    int* __restrict__ csr_src, int N)
{
    const int i = blockIdx.x * blockDim.x + threadIdx.x;
    if (i < N) {
        const int p = row_ptr[i];
        csr_src[p] = i;
        cursor[i] = p + 1;
    }
}

__global__ __launch_bounds__(256) void scatter_k(
    const int* __restrict__ esrc, const int* __restrict__ edst, int E,
    int* __restrict__ cursor, int* __restrict__ csr_src)
{
    const int stride = gridDim.x * blockDim.x;
    for (int e = blockIdx.x * blockDim.x + threadIdx.x; e < E; e += stride) {
        const int pos = atomicAdd(&cursor[edst[e]], 1);
        csr_src[pos] = esrc[e];
    }
}

// ---------------- CSR aggregation: one wave per node, single pass ----------------
__global__ __launch_bounds__(256) void csr_aggregate(
    const int* __restrict__ row_ptr, const int* __restrict__ csr_src,
    const float* __restrict__ h, const float2* __restrict__ as_,
    const float2* __restrict__ ad_, const float* __restrict__ bias,
    float* __restrict__ out, int N, int do_relu)
{
    const int lane = threadIdx.x & 63;
    const int node = (blockIdx.x * blockDim.x + threadIdx.x) >> 6;
    if (node >= N) return;

    const int start = row_ptr[node];
    const int end   = row_ptr[node + 1];
    const float2 ad = ad_[node];
    const float2* __restrict__ h2 = (const float2*)h;

    float den0 = 0.f, den1 = 0.f;
    float accx = 0.f, accy = 0.f;

    for (int base = start; base < end; base += 64) {
        const int cnt = min(64, end - base);
        float ex0 = 0.f, ex1 = 0.f;
        int s = 0;
        if (lane < cnt) {
            s = csr_src[base + lane];
            const float2 as = as_[s];
            float e0 = as.x + ad.x; e0 = fmaxf(e0, 0.2f * e0);   // leaky relu
            float e1 = as.y + ad.y; e1 = fmaxf(e1, 0.2f * e1);
            ex0 = __expf(e0); ex1 = __expf(e1);
            den0 += ex0; den1 += ex1;
        }
        for (int j = 0; j < cnt; ++j) {
            const int   sj = __shfl(s, j, 64);
            const float e0 = __shfl(ex0, j, 64);
            const float e1 = __shfl(ex1, j, 64);
            const float e  = (lane < 32) ? e0 : e1;
            const float2 hv = h2[(size_t)sj * 64 + lane];
            accx = fmaf(e, hv.x, accx);
            accy = fmaf(e, hv.y, accy);
        }
    }

#pragma unroll
    for (int off = 32; off; off >>= 1) {
        den0 += __shfl_xor(den0, off, 64);
        den1 += __shfl_xor(den1, off, 64);
    }
    const float rd = 1.f / ((lane < 32) ? den0 : den1);
    const float2 bv = ((const float2*)bias)[lane];
    float vx = fmaf(accx, rd, bv.x);
    float vy = fmaf(accy, rd, bv.y);
    if (do_relu) { vx = fmaxf(vx, 0.f); vy = fmaxf(vy, 0.f); }
    ((float2*)out)[(size_t)node * 64 + lane] = make_float2(vx, vy);
}

// ---------------- build rearranged decoder weight: Wuv[128][128] ----------------
__global__ void build_wuv(const float* __restrict__ lin1_w, float* __restrict__ Wuv)
{
    const int i = blockIdx.x * blockDim.x + threadIdx.x;
    if (i >= 128 * 128) return;
    const int k = i >> 7, j = i & 127;
    Wuv[i] = (j < 64) ? lin1_w[k * 64 + j] : lin1_w[(128 + k) * 64 + (j - 64)];
}

// ---------------- decoder: one wave per label edge ----------------
__global__ __launch_bounds__(256) void decode_k(
    const int* __restrict__ eli, int L_, const float* __restrict__ uv,
    const float* __restrict__ lin1_b, const float* __restrict__ lin2_w,
    const float* __restrict__ lin2_b, float* __restrict__ out)
{
    const int lane = threadIdx.x & 63;
    const int wstride = (gridDim.x * blockDim.x) >> 6;
    for (int wid = (blockIdx.x * blockDim.x + threadIdx.x) >> 6; wid < L_; wid += wstride) {
        const int a = eli[wid], b = eli[L_ + wid];
        float x = uv[(size_t)a * 128 + lane] + uv[(size_t)b * 128 + 64 + lane] + lin1_b[lane];
        x = x > 0.f ? x : 0.f;
        float p = x * lin2_w[lane];
#pragma unroll
        for (int off = 32; off; off >>= 1) p += __shfl_xor(p, off, 64);
        if (lane == 0) out[wid] = p + lin2_b[0];
    }
}

extern "C" void kernel_launch(void* const* d_in, const int* in_sizes, int n_in,
                              void* d_out, int out_size, void* d_ws, size_t ws_size,
                              hipStream_t stream)
{
    const float* x     = (const float*)d_in[0];
    const int*   ei    = (const int*)d_in[1];
    const int*   eli   = (const int*)d_in[2];
    const float* W1    = (const float*)d_in[3];
    const float* atts1 = (const float*)d_in[4];
    const float* attd1 = (const float*)d_in[5];
    const float* bias1 = (const float*)d_in[6];
    const float* W2    = (const float*)d_in[7];
    const float* atts2 = (const float*)d_in[8];
    const float* attd2 = (const float*)d_in[9];
    const float* bias2 = (const float*)d_in[10];
    const float* lin1w = (const float*)d_in[11];
    const float* lin1b = (const float*)d_in[12];
    const float* lin2w = (const float*)d_in[13];
    const float* lin2b = (const float*)d_in[14];
    float* out = (float*)d_out;

    const int N = in_sizes[0] / 128;
    const int E = in_sizes[1] / 2;
    const int L = in_sizes[2] / 2;

    float* ws   = (float*)d_ws;
    float* h    = ws;                        // N*128
    float* x2z  = h + (size_t)N * 128;       // N*128
    float* a_s  = x2z + (size_t)N * 128;     // N*2
    float* a_d  = a_s + (size_t)N * 2;       // N*2
    float* Wuv  = a_d + (size_t)N * 2;       // 128*128
    int* row_ptr = (int*)(Wuv + 128 * 128);  // N+1 (padded to N+4 for alignment)
    int* counts  = row_ptr + (N + 4);        // N   (16B-aligned: N+4 ints pad)
    int* cursor  = counts + N;               // N
    int* csr_src = cursor + N;               // E+N
    int* blockSums = csr_src + (E + N);      // nb

    const int GEMM_GRID  = 1250;
    const int attnBlocks = (N + 3) / 4;
    const int nBlocks256 = (N + 255) / 256;
    const int nb = (N + 1023) / 1024;        // scan chunks

    // ---- CSR build (once, reused by both layers) ----
    init_counts_k<<<nBlocks256, 256, 0, stream>>>(counts, N);
    hist_k<<<2048, 256, 0, stream>>>(ei + E, E, counts);
    scan_phase1<<<nb, 256, 0, stream>>>(counts, blockSums, N);
    scan_phase2<<<1, 256, 0, stream>>>(blockSums, nb, row_ptr, N);
    scan_phase3<<<nb, 256, 0, stream>>>(counts, blockSums, row_ptr, N);
    init_cursor_k<<<nBlocks256, 256, 0, stream>>>(row_ptr, cursor, csr_src, N);
    scatter_k<<<2048, 256, 0, stream>>>(ei, ei + E, E, cursor, csr_src);

    for (int layer = 0; layer < 2; ++layer) {
        const float* xin  = (layer == 0) ? x : x2z;
        const float* W    = (layer == 0) ? W1 : W2;
        const float* as_w = (layer == 0) ? atts1 : atts2;
        const float* ad_w = (layer == 0) ? attd1 : attd2;
        const float* bs   = (layer == 0) ? bias1 : bias2;

        gemm128<<<GEMM_GRID, 256, 0, stream>>>(xin, W, h, N);
        attn_coef<<<attnBlocks, 256, 0, stream>>>(h, as_w, ad_w,
                                                  (float2*)a_s, (float2*)a_d, N);
        csr_aggregate<<<(N + 3) / 4, 256, 0, stream>>>(row_ptr, csr_src, h,
                                                       (const float2*)a_s, (const float2*)a_d,
                                                       bs, x2z, N, (layer == 0) ? 1 : 0);
    }

    build_wuv<<<64, 256, 0, stream>>>(lin1w, Wuv);
    gemm128<<<GEMM_GRID, 256, 0, stream>>>(x2z, Wuv, h, N);   // h := uv
    decode_k<<<8192, 256, 0, stream>>>(eli, L, h, lin1b, lin2w, lin2b, out);
}

// Round 5
// 783.484 us; speedup vs baseline: 2.7582x; 1.0096x over previous
//
#include <hip/hip_runtime.h>

// GNN link predict: 2-layer GAT (H=2, C=64, HC=128) + factored MLP decoder.
// All fp32. Softmax max-subtraction skipped (alpha invariant to m; logits bounded).
// Aggregation: CSR (built once) -> one wave per node, readlane-broadcast gather,
// 4x unrolled for load ILP. GEMM: 64-row tiles, 8x4 thread tile, reg-prefetch.

__device__ __forceinline__ float rl_f(float v, int lane) {
    return __int_as_float(__builtin_amdgcn_readlane(__float_as_int(v), lane));
}

// ---------------- GEMM: Y[nrows,128] = X[nrows,128] @ W[128,128] ----------------
// Block 256 thr, 1 block/CU (96KB LDS). Thread (tr=t>>5, tc=t&31) owns rows
// 8*tr..8*tr+7, cols 4*tc..4*tc+3 of a 64x128 tile. Next tile prefetched to regs
// during compute, ds_written after barrier.
__global__ __launch_bounds__(256, 1) void gemm128(
    const float* __restrict__ X, const float* __restrict__ W,
    float* __restrict__ Y, int nrows)
{
    __shared__ float Wl[128 * 128];
    __shared__ float Xl[64 * 128];
    const int t = threadIdx.x;

    // stage W (once per block)
    for (int i = t * 4; i < 128 * 128; i += 256 * 4)
        *reinterpret_cast<float4*>(&Wl[i]) = *reinterpret_cast<const float4*>(&W[i]);

    const int tr = t >> 5;          // 0..7 -> rows 8*tr..8*tr+7
    const int tc = t & 31;          // cols 4*tc..4*tc+3
    const int prow = t >> 2;        // prefetch row within tile (4 thr/row)
    const int pcol = (t & 3) * 32;  // float offset within row

    float4 pf[8];
    auto load_pf = [&](int tbase) {
        const int r = tbase + prow;
        if (r < nrows) {
            const float* src = X + (size_t)r * 128 + pcol;
#pragma unroll
            for (int q = 0; q < 8; ++q)
                pf[q] = *reinterpret_cast<const float4*>(src + q * 4);
        } else {
#pragma unroll
            for (int q = 0; q < 8; ++q) pf[q] = make_float4(0.f, 0.f, 0.f, 0.f);
        }
    };

    int tile = blockIdx.x;
    const int tstride = gridDim.x;
    load_pf(tile * 64);

    for (; tile * 64 < nrows; tile += tstride) {
        __syncthreads();   // previous tile fully consumed (also fences W stage)
        {
            float* dst = &Xl[prow * 128 + pcol];
#pragma unroll
            for (int q = 0; q < 8; ++q)
                *reinterpret_cast<float4*>(dst + q * 4) = pf[q];
        }
        __syncthreads();

        const int nbase = (tile + tstride) * 64;
        if (nbase < nrows) load_pf(nbase);   // hidden under compute

        float4 acc[8];
#pragma unroll
        for (int i = 0; i < 8; ++i) acc[i] = make_float4(0.f, 0.f, 0.f, 0.f);

#pragma unroll 4
        for (int k = 0; k < 128; ++k) {
            const float4 wv = *reinterpret_cast<const float4*>(&Wl[k * 128 + tc * 4]);
#pragma unroll
            for (int i = 0; i < 8; ++i) {
                const float xv = Xl[(8 * tr + i) * 128 + k];
                acc[i].x = fmaf(xv, wv.x, acc[i].x);
                acc[i].y = fmaf(xv, wv.y, acc[i].y);
                acc[i].z = fmaf(xv, wv.z, acc[i].z);
                acc[i].w = fmaf(xv, wv.w, acc[i].w);
            }
        }

        const int r0 = tile * 64 + 8 * tr;
#pragma unroll
        for (int i = 0; i < 8; ++i) {
            if (r0 + i < nrows)
                *reinterpret_cast<float4*>(&Y[(size_t)(r0 + i) * 128 + tc * 4]) = acc[i];
        }
    }
}

// ---------------- attention coefficients: one wave per node ----------------
__global__ __launch_bounds__(256) void attn_coef(
    const float* __restrict__ h, const float* __restrict__ att_s,
    const float* __restrict__ att_d, float2* __restrict__ as_out,
    float2* __restrict__ ad_out, int n)
{
    const int wid = (blockIdx.x * blockDim.x + threadIdx.x) >> 6;
    const int lane = threadIdx.x & 63;
    if (wid >= n) return;
    const float* hr = h + (size_t)wid * 128;
    const float h0 = hr[lane];
    const float h1 = hr[64 + lane];
    float s0 = h0 * att_s[lane];
    float s1 = h1 * att_s[64 + lane];
    float d0 = h0 * att_d[lane];
    float d1 = h1 * att_d[64 + lane];
#pragma unroll
    for (int off = 32; off; off >>= 1) {
        s0 += __shfl_xor(s0, off, 64);
        s1 += __shfl_xor(s1, off, 64);
        d0 += __shfl_xor(d0, off, 64);
        d1 += __shfl_xor(d1, off, 64);
    }
    if (lane == 0) {
        as_out[wid] = make_float2(s0, s1);
        ad_out[wid] = make_float2(d0, d1);
    }
}

// ---------------- CSR build ----------------
__global__ __launch_bounds__(256) void init_counts_k(int* __restrict__ counts, int N)
{
    const int i = blockIdx.x * blockDim.x + threadIdx.x;
    if (i < N) counts[i] = 1;   // self-loop pre-counted
}

__global__ __launch_bounds__(256) void hist_k(
    const int* __restrict__ edst, int E, int* __restrict__ counts)
{
    const int stride = gridDim.x * blockDim.x;
    for (int e = blockIdx.x * blockDim.x + threadIdx.x; e < E; e += stride)
        atomicAdd(&counts[edst[e]], 1);
}

// ---- 3-phase hierarchical exclusive scan over counts[0..N) -> row_ptr[0..N] ----
__global__ __launch_bounds__(256) void scan_phase1(
    const int* __restrict__ counts, int* __restrict__ blockSums, int N)
{
    __shared__ int wsum[4];
    const int b = blockIdx.x, t = threadIdx.x;
    const int base = b * 1024 + t * 4;
    int s = 0;
    if (base + 3 < N) {
        const int4 c = *reinterpret_cast<const int4*>(&counts[base]);
        s = c.x + c.y + c.z + c.w;
    } else {
#pragma unroll
        for (int k = 0; k < 4; ++k) if (base + k < N) s += counts[base + k];
    }
#pragma unroll
    for (int off = 32; off; off >>= 1) s += __shfl_xor(s, off, 64);
    if ((t & 63) == 0) wsum[t >> 6] = s;
    __syncthreads();
    if (t == 0) blockSums[b] = wsum[0] + wsum[1] + wsum[2] + wsum[3];
}

__global__ __launch_bounds__(256) void scan_phase2(
    int* __restrict__ blockSums, int nb, int* __restrict__ row_ptr, int N)
{
    __shared__ int wsum[4];
    __shared__ int carry_sh;
    const int t = threadIdx.x;
    if (t == 0) carry_sh = 0;
    __syncthreads();
    for (int base = 0; base < nb; base += 256) {
        const int i = base + t;
        const int v = (i < nb) ? blockSums[i] : 0;
        int x = v;
#pragma unroll
        for (int off = 1; off < 64; off <<= 1) {
            const int y = __shfl_up(x, off, 64);
            if ((t & 63) >= off) x += y;
        }
        if ((t & 63) == 63) wsum[t >> 6] = x;
        __syncthreads();
        int woff = 0;
        for (int w = 0; w < (t >> 6); ++w) woff += wsum[w];
        const int carry = carry_sh;
        if (i < nb) blockSums[i] = carry + woff + x - v;
        __syncthreads();
        if (t == 255) carry_sh = carry + woff + x;
        __syncthreads();
    }
    if (t == 0) row_ptr[N] = carry_sh;
}

__global__ __launch_bounds__(256) void scan_phase3(
    const int* __restrict__ counts, const int* __restrict__ blockSums,
    int* __restrict__ row_ptr, int N)
{
    __shared__ int wsum[4];
    const int b = blockIdx.x, t = threadIdx.x;
    const int base = b * 1024 + t * 4;
    int v0 = 0, v1 = 0, v2 = 0, v3 = 0;
    if (base + 3 < N) {
        const int4 c = *reinterpret_cast<const int4*>(&counts[base]);
        v0 = c.x; v1 = c.y; v2 = c.z; v3 = c.w;
    } else {
        if (base + 0 < N) v0 = counts[base + 0];
        if (base + 1 < N) v1 = counts[base + 1];
        if (base + 2 < N) v2 = counts[base + 2];
        if (base + 3 < N) v3 = counts[base + 3];
    }
    const int tsum = v0 + v1 + v2 + v3;
    int x = tsum;
#pragma unroll
    for (int off = 1; off < 64; off <<= 1) {
        const int y = __shfl_up(x, off, 64);
        if ((t & 63) >= off) x += y;
    }
    if ((t & 63) == 63) wsum[t >> 6] = x;
    __syncthreads();
    int woff = 0;
    for (int w = 0; w < (t >> 6); ++w) woff += wsum[w];
    int excl = blockSums[b] + woff + x - tsum;
    if (base + 0 < N) row_ptr[base + 0] = excl;
    if (base + 1 < N) row_ptr[base + 1] = excl + v0;
    if (base + 2 < N) row_ptr[base + 2] = excl + v0 + v1;
    if (base + 3 < N) row_ptr[base + 3] = excl + v0 + v1 + v2;
}

__global__ __launch_bounds__(256) void init_cursor_k(
    const int* __restrict__ row_ptr, int* __restrict__ cursor,
    int* __restrict__ csr_src, int N)
{
    const int i = blockIdx.x * blockDim.x + threadIdx.x;
    if (i < N) {
        const int p = row_ptr[i];
        csr_src[p] = i;
        cursor[i] = p + 1;
    }
}

__global__ __launch_bounds__(256) void scatter_k(
    const int* __restrict__ esrc, const int* __restrict__ edst, int E,
    int* __restrict__ cursor, int* __restrict__ csr_src)
{
    const int stride = gridDim.x * blockDim.x;
    for (int e = blockIdx.x * blockDim.x + threadIdx.x; e < E; e += stride) {
        const int pos = atomicAdd(&cursor[edst[e]], 1);
        csr_src[pos] = esrc[e];
    }
}

// ---------------- CSR aggregation: one wave per node, single pass ----------------
// readlane (uniform j) broadcasts (s, ex0, ex1); 4x unroll -> 4 gathers in flight.
__global__ __launch_bounds__(256) void csr_aggregate(
    const int* __restrict__ row_ptr, const int* __restrict__ csr_src,
    const float* __restrict__ h, const float2* __restrict__ as_,
    const float2* __restrict__ ad_, const float* __restrict__ bias,
    float* __restrict__ out, int N, int do_relu)
{
    const int lane = threadIdx.x & 63;
    const int node = (blockIdx.x * blockDim.x + threadIdx.x) >> 6;
    if (node >= N) return;

    const int start = row_ptr[node];
    const int end   = row_ptr[node + 1];
    const float2 ad = ad_[node];
    const float2* __restrict__ h2 = (const float2*)h;
    const bool hi = lane >= 32;

    float den0 = 0.f, den1 = 0.f;
    float accx = 0.f, accy = 0.f;

    for (int base = start; base < end; base += 64) {
        const int cnt = min(64, end - base);
        float ex0 = 0.f, ex1 = 0.f;
        int s = 0;
        if (lane < cnt) {
            s = csr_src[base + lane];
            const float2 as = as_[s];
            float e0 = as.x + ad.x; e0 = fmaxf(e0, 0.2f * e0);   // leaky relu
            float e1 = as.y + ad.y; e1 = fmaxf(e1, 0.2f * e1);
            ex0 = __expf(e0); ex1 = __expf(e1);
            den0 += ex0; den1 += ex1;
        }
        int j = 0;
        for (; j + 4 <= cnt; j += 4) {
            const int sj0 = __builtin_amdgcn_readlane(s, j);
            const int sj1 = __builtin_amdgcn_readlane(s, j + 1);
            const int sj2 = __builtin_amdgcn_readlane(s, j + 2);
            const int sj3 = __builtin_amdgcn_readlane(s, j + 3);
            const float ea = hi ? rl_f(ex1, j)     : rl_f(ex0, j);
            const float eb = hi ? rl_f(ex1, j + 1) : rl_f(ex0, j + 1);
            const float ec = hi ? rl_f(ex1, j + 2) : rl_f(ex0, j + 2);
            const float ed = hi ? rl_f(ex1, j + 3) : rl_f(ex0, j + 3);
            const float2 h0 = h2[(size_t)sj0 * 64 + lane];
            const float2 h1 = h2[(size_t)sj1 * 64 + lane];
            const float2 h2v = h2[(size_t)sj2 * 64 + lane];
            const float2 h3 = h2[(size_t)sj3 * 64 + lane];
            accx = fmaf(ea, h0.x, accx); accy = fmaf(ea, h0.y, accy);
            accx = fmaf(eb, h1.x, accx); accy = fmaf(eb, h1.y, accy);
            accx = fmaf(ec, h2v.x, accx); accy = fmaf(ec, h2v.y, accy);
            accx = fmaf(ed, h3.x, accx); accy = fmaf(ed, h3.y, accy);
        }
        for (; j < cnt; ++j) {
            const int sj = __builtin_amdgcn_readlane(s, j);
            const float e = hi ? rl_f(ex1, j) : rl_f(ex0, j);
            const float2 hv = h2[(size_t)sj * 64 + lane];
            accx = fmaf(e, hv.x, accx);
            accy = fmaf(e, hv.y, accy);
        }
    }

#pragma unroll
    for (int off = 32; off; off >>= 1) {
        den0 += __shfl_xor(den0, off, 64);
        den1 += __shfl_xor(den1, off, 64);
    }
    const float rd = 1.f / (hi ? den1 : den0);
    const float2 bv = ((const float2*)bias)[lane];
    float vx = fmaf(accx, rd, bv.x);
    float vy = fmaf(accy, rd, bv.y);
    if (do_relu) { vx = fmaxf(vx, 0.f); vy = fmaxf(vy, 0.f); }
    ((float2*)out)[(size_t)node * 64 + lane] = make_float2(vx, vy);
}

// ---------------- build rearranged decoder weight: Wuv[128][128] ----------------
__global__ void build_wuv(const float* __restrict__ lin1_w, float* __restrict__ Wuv)
{
    const int i = blockIdx.x * blockDim.x + threadIdx.x;
    if (i >= 128 * 128) return;
    const int k = i >> 7, j = i & 127;
    Wuv[i] = (j < 64) ? lin1_w[k * 64 + j] : lin1_w[(128 + k) * 64 + (j - 64)];
}

// ---------------- decoder: one wave per label edge ----------------
__global__ __launch_bounds__(256) void decode_k(
    const int* __restrict__ eli, int L_, const float* __restrict__ uv,
    const float* __restrict__ lin1_b, const float* __restrict__ lin2_w,
    const float* __restrict__ lin2_b, float* __restrict__ out)
{
    const int lane = threadIdx.x & 63;
    const int wstride = (gridDim.x * blockDim.x) >> 6;
    for (int wid = (blockIdx.x * blockDim.x + threadIdx.x) >> 6; wid < L_; wid += wstride) {
        const int a = eli[wid], b = eli[L_ + wid];
        float x = uv[(size_t)a * 128 + lane] + uv[(size_t)b * 128 + 64 + lane] + lin1_b[lane];
        x = x > 0.f ? x : 0.f;
        float p = x * lin2_w[lane];
#pragma unroll
        for (int off = 32; off; off >>= 1) p += __shfl_xor(p, off, 64);
        if (lane == 0) out[wid] = p + lin2_b[0];
    }
}

extern "C" void kernel_launch(void* const* d_in, const int* in_sizes, int n_in,
                              void* d_out, int out_size, void* d_ws, size_t ws_size,
                              hipStream_t stream)
{
    const float* x     = (const float*)d_in[0];
    const int*   ei    = (const int*)d_in[1];
    const int*   eli   = (const int*)d_in[2];
    const float* W1    = (const float*)d_in[3];
    const float* atts1 = (const float*)d_in[4];
    const float* attd1 = (const float*)d_in[5];
    const float* bias1 = (const float*)d_in[6];
    const float* W2    = (const float*)d_in[7];
    const float* atts2 = (const float*)d_in[8];
    const float* attd2 = (const float*)d_in[9];
    const float* bias2 = (const float*)d_in[10];
    const float* lin1w = (const float*)d_in[11];
    const float* lin1b = (const float*)d_in[12];
    const float* lin2w = (const float*)d_in[13];
    const float* lin2b = (const float*)d_in[14];
    float* out = (float*)d_out;

    const int N = in_sizes[0] / 128;
    const int E = in_sizes[1] / 2;
    const int L = in_sizes[2] / 2;

    float* ws   = (float*)d_ws;
    float* h    = ws;                        // N*128
    float* x2z  = h + (size_t)N * 128;       // N*128
    float* a_s  = x2z + (size_t)N * 128;     // N*2
    float* a_d  = a_s + (size_t)N * 2;       // N*2
    float* Wuv  = a_d + (size_t)N * 2;       // 128*128
    int* row_ptr = (int*)(Wuv + 128 * 128);  // N+1 (padded to N+4 for alignment)
    int* counts  = row_ptr + (N + 4);        // N   (16B-aligned)
    int* cursor  = counts + N;               // N
    int* csr_src = cursor + N;               // E+N
    int* blockSums = csr_src + (E + N);      // nb

    const int attnBlocks = (N + 3) / 4;
    const int nBlocks256 = (N + 255) / 256;
    const int nb = (N + 1023) / 1024;        // scan chunks

    // ---- CSR build (once, reused by both layers) ----
    init_counts_k<<<nBlocks256, 256, 0, stream>>>(counts, N);
    hist_k<<<2048, 256, 0, stream>>>(ei + E, E, counts);
    scan_phase1<<<nb, 256, 0, stream>>>(counts, blockSums, N);
    scan_phase2<<<1, 256, 0, stream>>>(blockSums, nb, row_ptr, N);
    scan_phase3<<<nb, 256, 0, stream>>>(counts, blockSums, row_ptr, N);
    init_cursor_k<<<nBlocks256, 256, 0, stream>>>(row_ptr, cursor, csr_src, N);
    scatter_k<<<2048, 256, 0, stream>>>(ei, ei + E, E, cursor, csr_src);

    for (int layer = 0; layer < 2; ++layer) {
        const float* xin  = (layer == 0) ? x : x2z;
        const float* W    = (layer == 0) ? W1 : W2;
        const float* as_w = (layer == 0) ? atts1 : atts2;
        const float* ad_w = (layer == 0) ? attd1 : attd2;
        const float* bs   = (layer == 0) ? bias1 : bias2;

        gemm128<<<256, 256, 0, stream>>>(xin, W, h, N);
        attn_coef<<<attnBlocks, 256, 0, stream>>>(h, as_w, ad_w,
                                                  (float2*)a_s, (float2*)a_d, N);
        csr_aggregate<<<(N + 3) / 4, 256, 0, stream>>>(row_ptr, csr_src, h,
                                                       (const float2*)a_s, (const float2*)a_d,
                                                       bs, x2z, N, (layer == 0) ? 1 : 0);
    }

    build_wuv<<<64, 256, 0, stream>>>(lin1w, Wuv);
    gemm128<<<256, 256, 0, stream>>>(x2z, Wuv, h, N);   // h := uv
    decode_k<<<8192, 256, 0, stream>>>(eli, L, h, lin1b, lin2w, lin2b, out);
}

// Round 7
// 626.391 us; speedup vs baseline: 3.4499x; 1.2508x over previous
//
#include <hip/hip_runtime.h>
#include <hip/hip_fp16.h>

// GNN link predict: 2-layer GAT (H=2, C=64, HC=128) + factored MLP decoder.
// Gathered tables (h per layer, uv for decoder) stored fp16 to halve gather bytes;
// all accumulation fp32. Softmax max-subtraction skipped (alpha invariant to m).
// Aggregation: CSR (built once) -> one wave per node, readlane-broadcast, 8x ILP.

__device__ __forceinline__ float rl_f(float v, int lane) {
    return __int_as_float(__builtin_amdgcn_readlane(__float_as_int(v), lane));
}

// ---------------- GEMM: Y16[nrows,128](fp16) = X[nrows,128] @ W[128,128] ----------------
// 80KB LDS (W 64KB + 32-row X tile 16KB) -> 2 blocks/CU. Thread = 4 rows x 4 cols.
__global__ __launch_bounds__(256, 2) void gemm128_h(
    const float* __restrict__ X, const float* __restrict__ W,
    __half2* __restrict__ Y, int nrows)
{
    __shared__ float Wl[128 * 128];
    __shared__ float Xl[32 * 128];
    const int t = threadIdx.x;

    for (int i = t * 4; i < 128 * 128; i += 256 * 4)
        *reinterpret_cast<float4*>(&Wl[i]) = *reinterpret_cast<const float4*>(&W[i]);

    const int tr = (t >> 5) * 4;     // base row (4 rows)
    const int tc = t & 31;           // col group: cols 4*tc..4*tc+3
    const int prow = t >> 3;         // prefetch row (8 thr/row)
    const int pcol = (t & 7) * 16;   // 16 floats per thread

    float4 pf[4];
    auto load_pf = [&](int tbase) {
        const int r = tbase + prow;
        if (r < nrows) {
            const float* src = X + (size_t)r * 128 + pcol;
#pragma unroll
            for (int q = 0; q < 4; ++q)
                pf[q] = *reinterpret_cast<const float4*>(src + q * 4);
        } else {
#pragma unroll
            for (int q = 0; q < 4; ++q) pf[q] = make_float4(0.f, 0.f, 0.f, 0.f);
        }
    };

    int tile = blockIdx.x;
    const int tstride = gridDim.x;
    load_pf(tile * 32);

    for (; tile * 32 < nrows; tile += tstride) {
        __syncthreads();   // previous tile consumed (first iter: fences W stage)
        {
            float* dst = &Xl[prow * 128 + pcol];
#pragma unroll
            for (int q = 0; q < 4; ++q)
                *reinterpret_cast<float4*>(dst + q * 4) = pf[q];
        }
        __syncthreads();

        const int nbase = (tile + tstride) * 32;
        if (nbase < nrows) load_pf(nbase);   // hidden under compute

        float4 acc[4];
#pragma unroll
        for (int i = 0; i < 4; ++i) acc[i] = make_float4(0.f, 0.f, 0.f, 0.f);

#pragma unroll 4
        for (int k = 0; k < 128; ++k) {
            const float4 wv = *reinterpret_cast<const float4*>(&Wl[k * 128 + tc * 4]);
#pragma unroll
            for (int i = 0; i < 4; ++i) {
                const float xv = Xl[(tr + i) * 128 + k];
                acc[i].x = fmaf(xv, wv.x, acc[i].x);
                acc[i].y = fmaf(xv, wv.y, acc[i].y);
                acc[i].z = fmaf(xv, wv.z, acc[i].z);
                acc[i].w = fmaf(xv, wv.w, acc[i].w);
            }
        }

        const int r0 = tile * 32 + tr;
#pragma unroll
        for (int i = 0; i < 4; ++i) {
            if (r0 + i < nrows) {
                __half2* dst = Y + (size_t)(r0 + i) * 64 + tc * 2;
                dst[0] = __float22half2_rn(make_float2(acc[i].x, acc[i].y));
                dst[1] = __float22half2_rn(make_float2(acc[i].z, acc[i].w));
            }
        }
    }
}

// ---------------- attention coefficients: one wave per node (fp16 h) ----------------
// lane l covers channels {2l, 2l+1}; lanes 0..31 = head0, 32..63 = head1.
__global__ __launch_bounds__(256) void attn_coef(
    const __half2* __restrict__ h, const float* __restrict__ att_s,
    const float* __restrict__ att_d, float2* __restrict__ as_out,
    float2* __restrict__ ad_out, int n)
{
    const int wid = (blockIdx.x * blockDim.x + threadIdx.x) >> 6;
    const int lane = threadIdx.x & 63;
    if (wid >= n) return;
    const float2 f   = __half22float2(h[(size_t)wid * 64 + lane]);
    const float2 as2 = ((const float2*)att_s)[lane];
    const float2 ad2 = ((const float2*)att_d)[lane];
    float s = f.x * as2.x + f.y * as2.y;
    float d = f.x * ad2.x + f.y * ad2.y;
#pragma unroll
    for (int off = 16; off; off >>= 1) {
        s += __shfl_xor(s, off, 64);
        d += __shfl_xor(d, off, 64);
    }
    const float s_o = __shfl_xor(s, 32, 64);
    const float d_o = __shfl_xor(d, 32, 64);
    if (lane == 0) {
        as_out[wid] = make_float2(s, s_o);
        ad_out[wid] = make_float2(d, d_o);
    }
}

// ---------------- CSR build ----------------
__global__ __launch_bounds__(256) void init_counts_k(int* __restrict__ counts, int N)
{
    const int i = blockIdx.x * blockDim.x + threadIdx.x;
    if (i < N) counts[i] = 1;   // self-loop pre-counted
}

__global__ __launch_bounds__(256) void hist_k(
    const int* __restrict__ edst, int E, int* __restrict__ counts)
{
    const int stride = gridDim.x * blockDim.x;
    for (int e = blockIdx.x * blockDim.x + threadIdx.x; e < E; e += stride)
        atomicAdd(&counts[edst[e]], 1);
}

// ---- 3-phase hierarchical exclusive scan over counts[0..N) -> row_ptr[0..N] ----
__global__ __launch_bounds__(256) void scan_phase1(
    const int* __restrict__ counts, int* __restrict__ blockSums, int N)
{
    __shared__ int wsum[4];
    const int b = blockIdx.x, t = threadIdx.x;
    const int base = b * 1024 + t * 4;
    int s = 0;
    if (base + 3 < N) {
        const int4 c = *reinterpret_cast<const int4*>(&counts[base]);
        s = c.x + c.y + c.z + c.w;
    } else {
#pragma unroll
        for (int k = 0; k < 4; ++k) if (base + k < N) s += counts[base + k];
    }
#pragma unroll
    for (int off = 32; off; off >>= 1) s += __shfl_xor(s, off, 64);
    if ((t & 63) == 0) wsum[t >> 6] = s;
    __syncthreads();
    if (t == 0) blockSums[b] = wsum[0] + wsum[1] + wsum[2] + wsum[3];
}

__global__ __launch_bounds__(256) void scan_phase2(
    int* __restrict__ blockSums, int nb, int* __restrict__ row_ptr, int N)
{
    __shared__ int wsum[4];
    __shared__ int carry_sh;
    const int t = threadIdx.x;
    if (t == 0) carry_sh = 0;
    __syncthreads();
    for (int base = 0; base < nb; base += 256) {
        const int i = base + t;
        const int v = (i < nb) ? blockSums[i] : 0;
        int x = v;
#pragma unroll
        for (int off = 1; off < 64; off <<= 1) {
            const int y = __shfl_up(x, off, 64);
            if ((t & 63) >= off) x += y;
        }
        if ((t & 63) == 63) wsum[t >> 6] = x;
        __syncthreads();
        int woff = 0;
        for (int w = 0; w < (t >> 6); ++w) woff += wsum[w];
        const int carry = carry_sh;
        if (i < nb) blockSums[i] = carry + woff + x - v;
        __syncthreads();
        if (t == 255) carry_sh = carry + woff + x;
        __syncthreads();
    }
    if (t == 0) row_ptr[N] = carry_sh;
}

__global__ __launch_bounds__(256) void scan_phase3(
    const int* __restrict__ counts, const int* __restrict__ blockSums,
    int* __restrict__ row_ptr, int N)
{
    __shared__ int wsum[4];
    const int b = blockIdx.x, t = threadIdx.x;
    const int base = b * 1024 + t * 4;
    int v0 = 0, v1 = 0, v2 = 0, v3 = 0;
    if (base + 3 < N) {
        const int4 c = *reinterpret_cast<const int4*>(&counts[base]);
        v0 = c.x; v1 = c.y; v2 = c.z; v3 = c.w;
    } else {
        if (base + 0 < N) v0 = counts[base + 0];
        if (base + 1 < N) v1 = counts[base + 1];
        if (base + 2 < N) v2 = counts[base + 2];
        if (base + 3 < N) v3 = counts[base + 3];
    }
    const int tsum = v0 + v1 + v2 + v3;
    int x = tsum;
#pragma unroll
    for (int off = 1; off < 64; off <<= 1) {
        const int y = __shfl_up(x, off, 64);
        if ((t & 63) >= off) x += y;
    }
    if ((t & 63) == 63) wsum[t >> 6] = x;
    __syncthreads();
    int woff = 0;
    for (int w = 0; w < (t >> 6); ++w) woff += wsum[w];
    int excl = blockSums[b] + woff + x - tsum;
    if (base + 0 < N) row_ptr[base + 0] = excl;
    if (base + 1 < N) row_ptr[base + 1] = excl + v0;
    if (base + 2 < N) row_ptr[base + 2] = excl + v0 + v1;
    if (base + 3 < N) row_ptr[base + 3] = excl + v0 + v1 + v2;
}

__global__ __launch_bounds__(256) void init_cursor_k(
    const int* __restrict__ row_ptr, int* __restrict__ cursor,
    int* __restrict__ csr_src, int N)
{
    const int i = blockIdx.x * blockDim.x + threadIdx.x;
    if (i < N) {
        const int p = row_ptr[i];
        csr_src[p] = i;
        cursor[i] = p + 1;
    }
}

__global__ __launch_bounds__(256) void scatter_k(
    const int* __restrict__ esrc, const int* __restrict__ edst, int E,
    int* __restrict__ cursor, int* __restrict__ csr_src)
{
    const int stride = gridDim.x * blockDim.x;
    for (int e = blockIdx.x * blockDim.x + threadIdx.x; e < E; e += stride) {
        const int pos = atomicAdd(&cursor[edst[e]], 1);
        csr_src[pos] = esrc[e];
    }
}

// ---------------- CSR aggregation: one wave per node, fp16 gather, 8x ILP ----------------
__global__ __launch_bounds__(256) void csr_aggregate(
    const int* __restrict__ row_ptr, const int* __restrict__ csr_src,
    const __half2* __restrict__ h2, const float2* __restrict__ as_,
    const float2* __restrict__ ad_, const float* __restrict__ bias,
    float* __restrict__ out, int N, int do_relu)
{
    const int lane = threadIdx.x & 63;
    const int node = (blockIdx.x * blockDim.x + threadIdx.x) >> 6;
    if (node >= N) return;

    const int start = row_ptr[node];
    const int end   = row_ptr[node + 1];
    const float2 ad = ad_[node];
    const bool hi = lane >= 32;

    float den0 = 0.f, den1 = 0.f;
    float accx = 0.f, accy = 0.f;

    for (int base = start; base < end; base += 64) {
        const int cnt = min(64, end - base);
        float ex0 = 0.f, ex1 = 0.f;
        int s = 0;
        if (lane < cnt) {
            s = csr_src[base + lane];
            const float2 as = as_[s];
            float e0 = as.x + ad.x; e0 = fmaxf(e0, 0.2f * e0);   // leaky relu
            float e1 = as.y + ad.y; e1 = fmaxf(e1, 0.2f * e1);
            ex0 = __expf(e0); ex1 = __expf(e1);
            den0 += ex0; den1 += ex1;
        }
        int j = 0;
        for (; j + 8 <= cnt; j += 8) {
            int   sj[8];
            float ej[8];
            float2 hv[8];
#pragma unroll
            for (int q = 0; q < 8; ++q) {
                sj[q] = __builtin_amdgcn_readlane(s, j + q);
                ej[q] = hi ? rl_f(ex1, j + q) : rl_f(ex0, j + q);
            }
#pragma unroll
            for (int q = 0; q < 8; ++q)
                hv[q] = __half22float2(h2[(size_t)sj[q] * 64 + lane]);
#pragma unroll
            for (int q = 0; q < 8; ++q) {
                accx = fmaf(ej[q], hv[q].x, accx);
                accy = fmaf(ej[q], hv[q].y, accy);
            }
        }
        for (; j < cnt; ++j) {
            const int sj = __builtin_amdgcn_readlane(s, j);
            const float e = hi ? rl_f(ex1, j) : rl_f(ex0, j);
            const float2 hv = __half22float2(h2[(size_t)sj * 64 + lane]);
            accx = fmaf(e, hv.x, accx);
            accy = fmaf(e, hv.y, accy);
        }
    }

#pragma unroll
    for (int off = 32; off; off >>= 1) {
        den0 += __shfl_xor(den0, off, 64);
        den1 += __shfl_xor(den1, off, 64);
    }
    const float rd = 1.f / (hi ? den1 : den0);
    const float2 bv = ((const float2*)bias)[lane];
    float vx = fmaf(accx, rd, bv.x);
    float vy = fmaf(accy, rd, bv.y);
    if (do_relu) { vx = fmaxf(vx, 0.f); vy = fmaxf(vy, 0.f); }
    ((float2*)out)[(size_t)node * 64 + lane] = make_float2(vx, vy);
}

// ---------------- build rearranged decoder weight: Wuv[128][128] ----------------
__global__ void build_wuv(const float* __restrict__ lin1_w, float* __restrict__ Wuv)
{
    const int i = blockIdx.x * blockDim.x + threadIdx.x;
    if (i >= 128 * 128) return;
    const int k = i >> 7, j = i & 127;
    Wuv[i] = (j < 64) ? lin1_w[k * 64 + j] : lin1_w[(128 + k) * 64 + (j - 64)];
}

// ---------------- decoder: one wave per label edge (fp16 uv) ----------------
__global__ __launch_bounds__(256) void decode_k(
    const int* __restrict__ eli, int L_, const __half* __restrict__ uv,
    const float* __restrict__ lin1_b, const float* __restrict__ lin2_w,
    const float* __restrict__ lin2_b, float* __restrict__ out)
{
    const int lane = threadIdx.x & 63;
    const int wstride = (gridDim.x * blockDim.x) >> 6;
    for (int wid = (blockIdx.x * blockDim.x + threadIdx.x) >> 6; wid < L_; wid += wstride) {
        const int a = eli[wid], b = eli[L_ + wid];
        float x = __half2float(uv[(size_t)a * 128 + lane])
                + __half2float(uv[(size_t)b * 128 + 64 + lane]) + lin1_b[lane];
        x = x > 0.f ? x : 0.f;
        float p = x * lin2_w[lane];
#pragma unroll
        for (int off = 32; off; off >>= 1) p += __shfl_xor(p, off, 64);
        if (lane == 0) out[wid] = p + lin2_b[0];
    }
}

extern "C" void kernel_launch(void* const* d_in, const int* in_sizes, int n_in,
                              void* d_out, int out_size, void* d_ws, size_t ws_size,
                              hipStream_t stream)
{
    const float* x     = (const float*)d_in[0];
    const int*   ei    = (const int*)d_in[1];
    const int*   eli   = (const int*)d_in[2];
    const float* W1    = (const float*)d_in[3];
    const float* atts1 = (const float*)d_in[4];
    const float* attd1 = (const float*)d_in[5];
    const float* bias1 = (const float*)d_in[6];
    const float* W2    = (const float*)d_in[7];
    const float* atts2 = (const float*)d_in[8];
    const float* attd2 = (const float*)d_in[9];
    const float* bias2 = (const float*)d_in[10];
    const float* lin1w = (const float*)d_in[11];
    const float* lin1b = (const float*)d_in[12];
    const float* lin2w = (const float*)d_in[13];
    const float* lin2b = (const float*)d_in[14];
    float* out = (float*)d_out;

    const int N = in_sizes[0] / 128;
    const int E = in_sizes[1] / 2;
    const int L = in_sizes[2] / 2;

    float* ws   = (float*)d_ws;
    __half2* h16 = (__half2*)ws;                  // N*64 half2 = N*128 halfs = N*64 floats
    float* x2z  = ws + (size_t)N * 64;            // N*128  (FIX: was N*32 -> aliased h16)
    float* a_s  = x2z + (size_t)N * 128;          // N*2
    float* a_d  = a_s + (size_t)N * 2;            // N*2
    float* Wuv  = a_d + (size_t)N * 2;            // 128*128
    int* row_ptr = (int*)(Wuv + 128 * 128);       // N+1 (padded to N+4)
    int* counts  = row_ptr + (N + 4);             // N (16B-aligned)
    int* cursor  = counts + N;                    // N
    int* csr_src = cursor + N;                    // E+N
    int* blockSums = csr_src + (E + N);           // nb

    const int attnBlocks = (N + 3) / 4;
    const int nBlocks256 = (N + 255) / 256;
    const int nb = (N + 1023) / 1024;

    // ---- CSR build (once, reused by both layers) ----
    init_counts_k<<<nBlocks256, 256, 0, stream>>>(counts, N);
    hist_k<<<2048, 256, 0, stream>>>(ei + E, E, counts);
    scan_phase1<<<nb, 256, 0, stream>>>(counts, blockSums, N);
    scan_phase2<<<1, 256, 0, stream>>>(blockSums, nb, row_ptr, N);
    scan_phase3<<<nb, 256, 0, stream>>>(counts, blockSums, row_ptr, N);
    init_cursor_k<<<nBlocks256, 256, 0, stream>>>(row_ptr, cursor, csr_src, N);
    scatter_k<<<2048, 256, 0, stream>>>(ei, ei + E, E, cursor, csr_src);

    for (int layer = 0; layer < 2; ++layer) {
        const float* xin  = (layer == 0) ? x : x2z;
        const float* W    = (layer == 0) ? W1 : W2;
        const float* as_w = (layer == 0) ? atts1 : atts2;
        const float* ad_w = (layer == 0) ? attd1 : attd2;
        const float* bs   = (layer == 0) ? bias1 : bias2;

        gemm128_h<<<512, 256, 0, stream>>>(xin, W, h16, N);
        attn_coef<<<attnBlocks, 256, 0, stream>>>(h16, as_w, ad_w,
                                                  (float2*)a_s, (float2*)a_d, N);
        csr_aggregate<<<(N + 3) / 4, 256, 0, stream>>>(row_ptr, csr_src, h16,
                                                       (const float2*)a_s, (const float2*)a_d,
                                                       bs, x2z, N, (layer == 0) ? 1 : 0);
    }

    build_wuv<<<64, 256, 0, stream>>>(lin1w, Wuv);
    gemm128_h<<<512, 256, 0, stream>>>(x2z, Wuv, h16, N);   // h16 := uv (fp16)
    decode_k<<<8192, 256, 0, stream>>>(eli, L, (const __half*)h16, lin1b, lin2w, lin2b, out);
}

// Round 8
// 547.598 us; speedup vs baseline: 3.9463x; 1.1439x over previous
//
#include <hip/hip_runtime.h>
#include <hip/hip_fp16.h>

// GNN link predict: 2-layer GAT (H=2, C=64, HC=128) + factored MLP decoder.
// fp16 gather tables, fp32 accumulation. CSR built once; scatter is
// XCD-partitioned so csr_src stores coalesce in the owning XCD's L2.
// attn coefficients fused into the GEMM epilogue (shfl-tree reduce).

__device__ __forceinline__ float rl_f(float v, int lane) {
    return __int_as_float(__builtin_amdgcn_readlane(__float_as_int(v), lane));
}

// ---------------- GEMM + fused attn coef ----------------
// Y16[nrows,128](fp16) = X[nrows,128] @ W[128,128]; if as_out != nullptr also
// a_s[n]=h[n]·att_s, a_d[n]=h[n]·att_d per head. 80KB LDS -> 2 blocks/CU.
__global__ __launch_bounds__(256, 2) void gemm128_h(
    const float* __restrict__ X, const float* __restrict__ W,
    __half2* __restrict__ Y, int nrows,
    const float* __restrict__ att_s, const float* __restrict__ att_d,
    float2* __restrict__ as_out, float2* __restrict__ ad_out)
{
    __shared__ float Wl[128 * 128];
    __shared__ float Xl[32 * 128];
    const int t = threadIdx.x;

    for (int i = t * 4; i < 128 * 128; i += 256 * 4)
        *reinterpret_cast<float4*>(&Wl[i]) = *reinterpret_cast<const float4*>(&W[i]);

    const int tr = (t >> 5) * 4;     // base row (4 rows)
    const int tc = t & 31;           // col group: cols 4*tc..4*tc+3
    const int prow = t >> 3;         // prefetch row (8 thr/row)
    const int pcol = (t & 7) * 16;   // 16 floats per thread

    float4 pf[4];
    auto load_pf = [&](int tbase) {
        const int r = tbase + prow;
        if (r < nrows) {
            const float* src = X + (size_t)r * 128 + pcol;
#pragma unroll
            for (int q = 0; q < 4; ++q)
                pf[q] = *reinterpret_cast<const float4*>(src + q * 4);
        } else {
#pragma unroll
            for (int q = 0; q < 4; ++q) pf[q] = make_float4(0.f, 0.f, 0.f, 0.f);
        }
    };

    int tile = blockIdx.x;
    const int tstride = gridDim.x;
    load_pf(tile * 32);

    for (; tile * 32 < nrows; tile += tstride) {
        __syncthreads();   // previous tile consumed (first iter: fences W stage)
        {
            float* dst = &Xl[prow * 128 + pcol];
#pragma unroll
            for (int q = 0; q < 4; ++q)
                *reinterpret_cast<float4*>(dst + q * 4) = pf[q];
        }
        __syncthreads();

        const int nbase = (tile + tstride) * 32;
        if (nbase < nrows) load_pf(nbase);   // hidden under compute

        float4 acc[4];
#pragma unroll
        for (int i = 0; i < 4; ++i) acc[i] = make_float4(0.f, 0.f, 0.f, 0.f);

#pragma unroll 4
        for (int k = 0; k < 128; ++k) {
            const float4 wv = *reinterpret_cast<const float4*>(&Wl[k * 128 + tc * 4]);
#pragma unroll
            for (int i = 0; i < 4; ++i) {
                const float xv = Xl[(tr + i) * 128 + k];
                acc[i].x = fmaf(xv, wv.x, acc[i].x);
                acc[i].y = fmaf(xv, wv.y, acc[i].y);
                acc[i].z = fmaf(xv, wv.z, acc[i].z);
                acc[i].w = fmaf(xv, wv.w, acc[i].w);
            }
        }

        const int r0 = tile * 32 + tr;
#pragma unroll
        for (int i = 0; i < 4; ++i) {
            if (r0 + i < nrows) {
                __half2* dst = Y + (size_t)(r0 + i) * 64 + tc * 2;
                dst[0] = __float22half2_rn(make_float2(acc[i].x, acc[i].y));
                dst[1] = __float22half2_rn(make_float2(acc[i].z, acc[i].w));
            }
        }

        if (as_out) {
            // cols 4tc..4tc+3 are all in head (tc>>4); att_* flat [128].
            const float4 asv = *reinterpret_cast<const float4*>(&att_s[tc * 4]);
            const float4 adv = *reinterpret_cast<const float4*>(&att_d[tc * 4]);
#pragma unroll
            for (int i = 0; i < 4; ++i) {
                float ps = acc[i].x * asv.x + acc[i].y * asv.y
                         + acc[i].z * asv.z + acc[i].w * asv.w;
                float pd = acc[i].x * adv.x + acc[i].y * adv.y
                         + acc[i].z * adv.z + acc[i].w * adv.w;
#pragma unroll
                for (int off = 1; off < 16; off <<= 1) {
                    ps += __shfl_xor(ps, off, 64);
                    pd += __shfl_xor(pd, off, 64);
                }
                const float ps_o = __shfl_xor(ps, 16, 64);   // other head's sum
                const float pd_o = __shfl_xor(pd, 16, 64);
                if ((t & 31) == 0 && r0 + i < nrows) {
                    as_out[r0 + i] = make_float2(ps, ps_o);
                    ad_out[r0 + i] = make_float2(pd, pd_o);
                }
            }
        }
    }
}

// ---------------- CSR build ----------------
__global__ __launch_bounds__(256) void init_counts_k(int* __restrict__ counts, int N)
{
    const int i = blockIdx.x * blockDim.x + threadIdx.x;
    if (i < N) counts[i] = 1;   // self-loop pre-counted
}

__global__ __launch_bounds__(256) void hist_k(
    const int* __restrict__ edst, int E, int* __restrict__ counts)
{
    const int stride = gridDim.x * blockDim.x;
    for (int e = blockIdx.x * blockDim.x + threadIdx.x; e < E; e += stride)
        atomicAdd(&counts[edst[e]], 1);
}

// ---- 3-phase hierarchical exclusive scan over counts[0..N) -> row_ptr[0..N] ----
__global__ __launch_bounds__(256) void scan_phase1(
    const int* __restrict__ counts, int* __restrict__ blockSums, int N)
{
    __shared__ int wsum[4];
    const int b = blockIdx.x, t = threadIdx.x;
    const int base = b * 1024 + t * 4;
    int s = 0;
    if (base + 3 < N) {
        const int4 c = *reinterpret_cast<const int4*>(&counts[base]);
        s = c.x + c.y + c.z + c.w;
    } else {
#pragma unroll
        for (int k = 0; k < 4; ++k) if (base + k < N) s += counts[base + k];
    }
#pragma unroll
    for (int off = 32; off; off >>= 1) s += __shfl_xor(s, off, 64);
    if ((t & 63) == 0) wsum[t >> 6] = s;
    __syncthreads();
    if (t == 0) blockSums[b] = wsum[0] + wsum[1] + wsum[2] + wsum[3];
}

__global__ __launch_bounds__(256) void scan_phase2(
    int* __restrict__ blockSums, int nb, int* __restrict__ row_ptr, int N)
{
    __shared__ int wsum[4];
    __shared__ int carry_sh;
    const int t = threadIdx.x;
    if (t == 0) carry_sh = 0;
    __syncthreads();
    for (int base = 0; base < nb; base += 256) {
        const int i = base + t;
        const int v = (i < nb) ? blockSums[i] : 0;
        int x = v;
#pragma unroll
        for (int off = 1; off < 64; off <<= 1) {
            const int y = __shfl_up(x, off, 64);
            if ((t & 63) >= off) x += y;
        }
        if ((t & 63) == 63) wsum[t >> 6] = x;
        __syncthreads();
        int woff = 0;
        for (int w = 0; w < (t >> 6); ++w) woff += wsum[w];
        const int carry = carry_sh;
        if (i < nb) blockSums[i] = carry + woff + x - v;
        __syncthreads();
        if (t == 255) carry_sh = carry + woff + x;
        __syncthreads();
    }
    if (t == 0) row_ptr[N] = carry_sh;
}

__global__ __launch_bounds__(256) void scan_phase3(
    const int* __restrict__ counts, const int* __restrict__ blockSums,
    int* __restrict__ row_ptr, int N)
{
    __shared__ int wsum[4];
    const int b = blockIdx.x, t = threadIdx.x;
    const int base = b * 1024 + t * 4;
    int v0 = 0, v1 = 0, v2 = 0, v3 = 0;
    if (base + 3 < N) {
        const int4 c = *reinterpret_cast<const int4*>(&counts[base]);
        v0 = c.x; v1 = c.y; v2 = c.z; v3 = c.w;
    } else {
        if (base + 0 < N) v0 = counts[base + 0];
        if (base + 1 < N) v1 = counts[base + 1];
        if (base + 2 < N) v2 = counts[base + 2];
        if (base + 3 < N) v3 = counts[base + 3];
    }
    const int tsum = v0 + v1 + v2 + v3;
    int x = tsum;
#pragma unroll
    for (int off = 1; off < 64; off <<= 1) {
        const int y = __shfl_up(x, off, 64);
        if ((t & 63) >= off) x += y;
    }
    if ((t & 63) == 63) wsum[t >> 6] = x;
    __syncthreads();
    int woff = 0;
    for (int w = 0; w < (t >> 6); ++w) woff += wsum[w];
    int excl = blockSums[b] + woff + x - tsum;
    if (base + 0 < N) row_ptr[base + 0] = excl;
    if (base + 1 < N) row_ptr[base + 1] = excl + v0;
    if (base + 2 < N) row_ptr[base + 2] = excl + v0 + v1;
    if (base + 3 < N) row_ptr[base + 3] = excl + v0 + v1 + v2;
}

__global__ __launch_bounds__(256) void init_cursor_k(
    const int* __restrict__ row_ptr, int* __restrict__ cursor,
    int* __restrict__ csr_src, int N)
{
    const int i = blockIdx.x * blockDim.x + threadIdx.x;
    if (i < N) {
        const int p = row_ptr[i];
        csr_src[p] = i;
        cursor[i] = p + 1;
    }
}

// XCD-partitioned scatter: partition p = blockIdx&7 handles dst in
// [p*npp, (p+1)*npp). All csr_src stores for a line then come from one XCD
// (heuristic blockIdx%8->XCD), so lines fill completely in that L2 before
// eviction. Correct regardless of the actual block->XCD mapping.
__global__ __launch_bounds__(256) void scatter_xcd_k(
    const int* __restrict__ esrc, const int* __restrict__ edst, int E,
    int* __restrict__ cursor, int* __restrict__ csr_src, int npp)
{
    const int part = blockIdx.x & 7;
    const int lo = part * npp;
    const int hiN = lo + npp;
    const int bi = blockIdx.x >> 3;
    const int stride = (gridDim.x >> 3) * blockDim.x;
    for (int e = bi * blockDim.x + threadIdx.x; e < E; e += stride) {
        const int d = edst[e];
        if (d >= lo && d < hiN) {
            const int pos = atomicAdd(&cursor[d], 1);
            csr_src[pos] = esrc[e];
        }
    }
}

// ---------------- CSR aggregation: one wave per node, fp16 gather, 8x ILP ----------------
__global__ __launch_bounds__(256) void csr_aggregate(
    const int* __restrict__ row_ptr, const int* __restrict__ csr_src,
    const __half2* __restrict__ h2, const float2* __restrict__ as_,
    const float2* __restrict__ ad_, const float* __restrict__ bias,
    float* __restrict__ out, int N, int do_relu)
{
    const int lane = threadIdx.x & 63;
    const int node = (blockIdx.x * blockDim.x + threadIdx.x) >> 6;
    if (node >= N) return;

    const int start = row_ptr[node];
    const int end   = row_ptr[node + 1];
    const float2 ad = ad_[node];
    const bool hi = lane >= 32;

    float den0 = 0.f, den1 = 0.f;
    float accx = 0.f, accy = 0.f;

    for (int base = start; base < end; base += 64) {
        const int cnt = min(64, end - base);
        float ex0 = 0.f, ex1 = 0.f;
        int s = 0;
        if (lane < cnt) {
            s = csr_src[base + lane];
            const float2 as = as_[s];
            float e0 = as.x + ad.x; e0 = fmaxf(e0, 0.2f * e0);   // leaky relu
            float e1 = as.y + ad.y; e1 = fmaxf(e1, 0.2f * e1);
            ex0 = __expf(e0); ex1 = __expf(e1);
            den0 += ex0; den1 += ex1;
        }
        int j = 0;
        for (; j + 8 <= cnt; j += 8) {
            int   sj[8];
            float ej[8];
            float2 hv[8];
#pragma unroll
            for (int q = 0; q < 8; ++q) {
                sj[q] = __builtin_amdgcn_readlane(s, j + q);
                ej[q] = hi ? rl_f(ex1, j + q) : rl_f(ex0, j + q);
            }
#pragma unroll
            for (int q = 0; q < 8; ++q)
                hv[q] = __half22float2(h2[(size_t)sj[q] * 64 + lane]);
#pragma unroll
            for (int q = 0; q < 8; ++q) {
                accx = fmaf(ej[q], hv[q].x, accx);
                accy = fmaf(ej[q], hv[q].y, accy);
            }
        }
        for (; j < cnt; ++j) {
            const int sj = __builtin_amdgcn_readlane(s, j);
            const float e = hi ? rl_f(ex1, j) : rl_f(ex0, j);
            const float2 hv = __half22float2(h2[(size_t)sj * 64 + lane]);
            accx = fmaf(e, hv.x, accx);
            accy = fmaf(e, hv.y, accy);
        }
    }

#pragma unroll
    for (int off = 32; off; off >>= 1) {
        den0 += __shfl_xor(den0, off, 64);
        den1 += __shfl_xor(den1, off, 64);
    }
    const float rd = 1.f / (hi ? den1 : den0);
    const float2 bv = ((const float2*)bias)[lane];
    float vx = fmaf(accx, rd, bv.x);
    float vy = fmaf(accy, rd, bv.y);
    if (do_relu) { vx = fmaxf(vx, 0.f); vy = fmaxf(vy, 0.f); }
    ((float2*)out)[(size_t)node * 64 + lane] = make_float2(vx, vy);
}

// ---------------- build rearranged decoder weight: Wuv[128][128] ----------------
__global__ void build_wuv(const float* __restrict__ lin1_w, float* __restrict__ Wuv)
{
    const int i = blockIdx.x * blockDim.x + threadIdx.x;
    if (i >= 128 * 128) return;
    const int k = i >> 7, j = i & 127;
    Wuv[i] = (j < 64) ? lin1_w[k * 64 + j] : lin1_w[(128 + k) * 64 + (j - 64)];
}

// ---------------- decoder: one wave per label edge (fp16 uv) ----------------
__global__ __launch_bounds__(256) void decode_k(
    const int* __restrict__ eli, int L_, const __half* __restrict__ uv,
    const float* __restrict__ lin1_b, const float* __restrict__ lin2_w,
    const float* __restrict__ lin2_b, float* __restrict__ out)
{
    const int lane = threadIdx.x & 63;
    const int wstride = (gridDim.x * blockDim.x) >> 6;
    for (int wid = (blockIdx.x * blockDim.x + threadIdx.x) >> 6; wid < L_; wid += wstride) {
        const int a = eli[wid], b = eli[L_ + wid];
        float x = __half2float(uv[(size_t)a * 128 + lane])
                + __half2float(uv[(size_t)b * 128 + 64 + lane]) + lin1_b[lane];
        x = x > 0.f ? x : 0.f;
        float p = x * lin2_w[lane];
#pragma unroll
        for (int off = 32; off; off >>= 1) p += __shfl_xor(p, off, 64);
        if (lane == 0) out[wid] = p + lin2_b[0];
    }
}

extern "C" void kernel_launch(void* const* d_in, const int* in_sizes, int n_in,
                              void* d_out, int out_size, void* d_ws, size_t ws_size,
                              hipStream_t stream)
{
    const float* x     = (const float*)d_in[0];
    const int*   ei    = (const int*)d_in[1];
    const int*   eli   = (const int*)d_in[2];
    const float* W1    = (const float*)d_in[3];
    const float* atts1 = (const float*)d_in[4];
    const float* attd1 = (const float*)d_in[5];
    const float* bias1 = (const float*)d_in[6];
    const float* W2    = (const float*)d_in[7];
    const float* atts2 = (const float*)d_in[8];
    const float* attd2 = (const float*)d_in[9];
    const float* bias2 = (const float*)d_in[10];
    const float* lin1w = (const float*)d_in[11];
    const float* lin1b = (const float*)d_in[12];
    const float* lin2w = (const float*)d_in[13];
    const float* lin2b = (const float*)d_in[14];
    float* out = (float*)d_out;

    const int N = in_sizes[0] / 128;
    const int E = in_sizes[1] / 2;
    const int L = in_sizes[2] / 2;

    float* ws   = (float*)d_ws;
    __half2* h16 = (__half2*)ws;                  // N*64 half2 = N*128 halfs
    float* x2z  = ws + (size_t)N * 64;            // N*128
    float* a_s  = x2z + (size_t)N * 128;          // N*2
    float* a_d  = a_s + (size_t)N * 2;            // N*2
    float* Wuv  = a_d + (size_t)N * 2;            // 128*128
    int* row_ptr = (int*)(Wuv + 128 * 128);       // N+1 (padded to N+4)
    int* counts  = row_ptr + (N + 4);             // N (16B-aligned)
    int* cursor  = counts + N;                    // N
    int* csr_src = cursor + N;                    // E+N
    int* blockSums = csr_src + (E + N);           // nb

    const int nBlocks256 = (N + 255) / 256;
    const int nb = (N + 1023) / 1024;
    const int npp = (N + 7) / 8;                  // nodes per XCD partition

    // ---- CSR build (once, reused by both layers) ----
    init_counts_k<<<nBlocks256, 256, 0, stream>>>(counts, N);
    hist_k<<<2048, 256, 0, stream>>>(ei + E, E, counts);
    scan_phase1<<<nb, 256, 0, stream>>>(counts, blockSums, N);
    scan_phase2<<<1, 256, 0, stream>>>(blockSums, nb, row_ptr, N);
    scan_phase3<<<nb, 256, 0, stream>>>(counts, blockSums, row_ptr, N);
    init_cursor_k<<<nBlocks256, 256, 0, stream>>>(row_ptr, cursor, csr_src, N);
    scatter_xcd_k<<<2048, 256, 0, stream>>>(ei, ei + E, E, cursor, csr_src, npp);

    for (int layer = 0; layer < 2; ++layer) {
        const float* xin  = (layer == 0) ? x : x2z;
        const float* W    = (layer == 0) ? W1 : W2;
        const float* as_w = (layer == 0) ? atts1 : atts2;
        const float* ad_w = (layer == 0) ? attd1 : attd2;
        const float* bs   = (layer == 0) ? bias1 : bias2;

        gemm128_h<<<512, 256, 0, stream>>>(xin, W, h16, N, as_w, ad_w,
                                           (float2*)a_s, (float2*)a_d);
        csr_aggregate<<<(N + 3) / 4, 256, 0, stream>>>(row_ptr, csr_src, h16,
                                                       (const float2*)a_s, (const float2*)a_d,
                                                       bs, x2z, N, (layer == 0) ? 1 : 0);
    }

    build_wuv<<<64, 256, 0, stream>>>(lin1w, Wuv);
    gemm128_h<<<512, 256, 0, stream>>>(x2z, Wuv, h16, N, nullptr, nullptr, nullptr, nullptr);
    decode_k<<<8192, 256, 0, stream>>>(eli, L, (const __half*)h16, lin1b, lin2w, lin2b, out);
}

// Round 9
// 459.254 us; speedup vs baseline: 4.7054x; 1.1924x over previous
//
#include <hip/hip_runtime.h>
#include <hip/hip_fp16.h>

// GNN link predict: 2-layer GAT (H=2, C=64, HC=128) + factored MLP decoder.
// GEMMs via v_mfma_f32_16x16x32_f16 (fp16 in, fp32 accum) with fused attn coefs.
// fp16 gather tables; CSR built once; XCD-partitioned scatter; 32-bit gather offsets.

typedef _Float16 f16x8 __attribute__((ext_vector_type(8)));
typedef float f32x4 __attribute__((ext_vector_type(4)));

__device__ __forceinline__ float rl_f(float v, int lane) {
    return __int_as_float(__builtin_amdgcn_readlane(__float_as_int(v), lane));
}

// ---------------- MFMA GEMM: Y16[nrows,128](fp16) = X[nrows,128]fp32 @ W[128,128]fp32 ----------------
// Block 256 thr = 4 waves; 64-row tile, 16-row strip/wave. LDS: W^T fp16 [128][136]
// + A fp16 [64][136] = 52KB -> 3 blocks/CU. C layout (verified): col=lane&15,
// row=(lane>>4)*4+reg. A/B k-permutation cancels between operands.
#define WT_LD 136
__global__ __launch_bounds__(256, 3) void gemm_mfma(
    const float* __restrict__ X, const float* __restrict__ W,
    _Float16* __restrict__ Y, int nrows,
    const float* __restrict__ att_s, const float* __restrict__ att_d,
    float2* __restrict__ as_out, float2* __restrict__ ad_out)
{
    __shared__ _Float16 WT[128 * WT_LD];
    __shared__ _Float16 At[64 * WT_LD];
    const int t = threadIdx.x;
    const int lane = t & 63;
    const int wid = t >> 6;

    // stage W^T as fp16: WT[n][k] = W[k][n]  (one-time per block)
    for (int i = t; i < 128 * 32; i += 256) {
        const int k = i >> 5;
        const int n4 = (i & 31) * 4;
        const float4 wv = *reinterpret_cast<const float4*>(&W[k * 128 + n4]);
        WT[(n4 + 0) * WT_LD + k] = (_Float16)wv.x;
        WT[(n4 + 1) * WT_LD + k] = (_Float16)wv.y;
        WT[(n4 + 2) * WT_LD + k] = (_Float16)wv.z;
        WT[(n4 + 3) * WT_LD + k] = (_Float16)wv.w;
    }

    const int am = lane & 15, ag = lane >> 4;

    float asv[8], adv[8];
    if (as_out) {
#pragma unroll
        for (int n0 = 0; n0 < 8; ++n0) {
            asv[n0] = att_s[n0 * 16 + am];
            adv[n0] = att_d[n0 * 16 + am];
        }
    }

    const int ntiles = (nrows + 63) >> 6;
    for (int tile = blockIdx.x; tile < ntiles; tile += gridDim.x) {
        const int rbase = tile * 64;
        __syncthreads();   // prev A consumed; first iter fences WT staging
        {
            const int r = t >> 2;
            const int c0 = (t & 3) * 32;      // halfs
            const int gr = rbase + r;
            _Float16 tmp[32];
            if (gr < nrows) {
                const float* src = X + (size_t)gr * 128 + c0;
#pragma unroll
                for (int q = 0; q < 8; ++q) {
                    const float4 v = *reinterpret_cast<const float4*>(src + q * 4);
                    tmp[q * 4 + 0] = (_Float16)v.x; tmp[q * 4 + 1] = (_Float16)v.y;
                    tmp[q * 4 + 2] = (_Float16)v.z; tmp[q * 4 + 3] = (_Float16)v.w;
                }
            } else {
#pragma unroll
                for (int q = 0; q < 32; ++q) tmp[q] = (_Float16)0.f;
            }
#pragma unroll
            for (int q = 0; q < 4; ++q)
                *reinterpret_cast<f16x8*>(&At[r * WT_LD + c0 + q * 8]) =
                    *reinterpret_cast<const f16x8*>(&tmp[q * 8]);
        }
        __syncthreads();

        const int srow = wid * 16;
        f16x8 a[4];
#pragma unroll
        for (int kb = 0; kb < 4; ++kb)
            a[kb] = *reinterpret_cast<const f16x8*>(
                &At[(srow + am) * WT_LD + kb * 32 + ag * 8]);

        f32x4 acc[8];
#pragma unroll
        for (int n0 = 0; n0 < 8; ++n0) {
            f32x4 c = {0.f, 0.f, 0.f, 0.f};
#pragma unroll
            for (int kb = 0; kb < 4; ++kb) {
                const f16x8 b = *reinterpret_cast<const f16x8*>(
                    &WT[(n0 * 16 + am) * WT_LD + kb * 32 + ag * 8]);
                c = __builtin_amdgcn_mfma_f32_16x16x32_f16(a[kb], b, c, 0, 0, 0);
            }
            acc[n0] = c;
        }

        const int growbase = rbase + srow + ag * 4;

        // store C as fp16
#pragma unroll
        for (int j = 0; j < 4; ++j) {
            const int grow = growbase + j;
            if (grow < nrows) {
#pragma unroll
                for (int n0 = 0; n0 < 8; ++n0)
                    Y[(size_t)grow * 128 + n0 * 16 + am] = (_Float16)acc[n0][j];
            }
        }

        // fused attn coefficients: per-row dots vs att_src/att_dst
        if (as_out) {
#pragma unroll
            for (int j = 0; j < 4; ++j) {
                float s0 = 0.f, s1 = 0.f, d0 = 0.f, d1 = 0.f;
#pragma unroll
                for (int n0 = 0; n0 < 4; ++n0) {
                    s0 = fmaf(acc[n0][j], asv[n0], s0);
                    d0 = fmaf(acc[n0][j], adv[n0], d0);
                }
#pragma unroll
                for (int n0 = 4; n0 < 8; ++n0) {
                    s1 = fmaf(acc[n0][j], asv[n0], s1);
                    d1 = fmaf(acc[n0][j], adv[n0], d1);
                }
#pragma unroll
                for (int off = 1; off < 16; off <<= 1) {
                    s0 += __shfl_xor(s0, off, 64); s1 += __shfl_xor(s1, off, 64);
                    d0 += __shfl_xor(d0, off, 64); d1 += __shfl_xor(d1, off, 64);
                }
                const int grow = growbase + j;
                if (am == 0 && grow < nrows) {
                    as_out[grow] = make_float2(s0, s1);
                    ad_out[grow] = make_float2(d0, d1);
                }
            }
        }
    }
}

// ---------------- CSR build ----------------
__global__ __launch_bounds__(256) void init_counts_k(int* __restrict__ counts, int N)
{
    const int i = blockIdx.x * blockDim.x + threadIdx.x;
    if (i < N) counts[i] = 1;   // self-loop pre-counted
}

__global__ __launch_bounds__(256) void hist_k(
    const int* __restrict__ edst, int E, int* __restrict__ counts)
{
    const int stride = gridDim.x * blockDim.x;
    for (int e = blockIdx.x * blockDim.x + threadIdx.x; e < E; e += stride)
        atomicAdd(&counts[edst[e]], 1);
}

__global__ __launch_bounds__(256) void scan_phase1(
    const int* __restrict__ counts, int* __restrict__ blockSums, int N)
{
    __shared__ int wsum[4];
    const int b = blockIdx.x, t = threadIdx.x;
    const int base = b * 1024 + t * 4;
    int s = 0;
    if (base + 3 < N) {
        const int4 c = *reinterpret_cast<const int4*>(&counts[base]);
        s = c.x + c.y + c.z + c.w;
    } else {
#pragma unroll
        for (int k = 0; k < 4; ++k) if (base + k < N) s += counts[base + k];
    }
#pragma unroll
    for (int off = 32; off; off >>= 1) s += __shfl_xor(s, off, 64);
    if ((t & 63) == 0) wsum[t >> 6] = s;
    __syncthreads();
    if (t == 0) blockSums[b] = wsum[0] + wsum[1] + wsum[2] + wsum[3];
}

__global__ __launch_bounds__(256) void scan_phase2(
    int* __restrict__ blockSums, int nb, int* __restrict__ row_ptr, int N)
{
    __shared__ int wsum[4];
    __shared__ int carry_sh;
    const int t = threadIdx.x;
    if (t == 0) carry_sh = 0;
    __syncthreads();
    for (int base = 0; base < nb; base += 256) {
        const int i = base + t;
        const int v = (i < nb) ? blockSums[i] : 0;
        int x = v;
#pragma unroll
        for (int off = 1; off < 64; off <<= 1) {
            const int y = __shfl_up(x, off, 64);
            if ((t & 63) >= off) x += y;
        }
        if ((t & 63) == 63) wsum[t >> 6] = x;
        __syncthreads();
        int woff = 0;
        for (int w = 0; w < (t >> 6); ++w) woff += wsum[w];
        const int carry = carry_sh;
        if (i < nb) blockSums[i] = carry + woff + x - v;
        __syncthreads();
        if (t == 255) carry_sh = carry + woff + x;
        __syncthreads();
    }
    if (t == 0) row_ptr[N] = carry_sh;
}

__global__ __launch_bounds__(256) void scan_phase3(
    const int* __restrict__ counts, const int* __restrict__ blockSums,
    int* __restrict__ row_ptr, int N)
{
    __shared__ int wsum[4];
    const int b = blockIdx.x, t = threadIdx.x;
    const int base = b * 1024 + t * 4;
    int v0 = 0, v1 = 0, v2 = 0, v3 = 0;
    if (base + 3 < N) {
        const int4 c = *reinterpret_cast<const int4*>(&counts[base]);
        v0 = c.x; v1 = c.y; v2 = c.z; v3 = c.w;
    } else {
        if (base + 0 < N) v0 = counts[base + 0];
        if (base + 1 < N) v1 = counts[base + 1];
        if (base + 2 < N) v2 = counts[base + 2];
        if (base + 3 < N) v3 = counts[base + 3];
    }
    const int tsum = v0 + v1 + v2 + v3;
    int x = tsum;
#pragma unroll
    for (int off = 1; off < 64; off <<= 1) {
        const int y = __shfl_up(x, off, 64);
        if ((t & 63) >= off) x += y;
    }
    if ((t & 63) == 63) wsum[t >> 6] = x;
    __syncthreads();
    int woff = 0;
    for (int w = 0; w < (t >> 6); ++w) woff += wsum[w];
    int excl = blockSums[b] + woff + x - tsum;
    if (base + 0 < N) row_ptr[base + 0] = excl;
    if (base + 1 < N) row_ptr[base + 1] = excl + v0;
    if (base + 2 < N) row_ptr[base + 2] = excl + v0 + v1;
    if (base + 3 < N) row_ptr[base + 3] = excl + v0 + v1 + v2;
}

__global__ __launch_bounds__(256) void init_cursor_k(
    const int* __restrict__ row_ptr, int* __restrict__ cursor,
    int* __restrict__ csr_src, int N)
{
    const int i = blockIdx.x * blockDim.x + threadIdx.x;
    if (i < N) {
        const int p = row_ptr[i];
        csr_src[p] = i;
        cursor[i] = p + 1;
    }
}

// XCD-partitioned scatter (see r7): partition p=blockIdx&7 handles dst range p.
__global__ __launch_bounds__(256) void scatter_xcd_k(
    const int* __restrict__ esrc, const int* __restrict__ edst, int E,
    int* __restrict__ cursor, int* __restrict__ csr_src, int npp)
{
    const int part = blockIdx.x & 7;
    const int lo = part * npp;
    const int hiN = lo + npp;
    const int bi = blockIdx.x >> 3;
    const int stride = (gridDim.x >> 3) * blockDim.x;
    for (int e = bi * blockDim.x + threadIdx.x; e < E; e += stride) {
        const int d = edst[e];
        if (d >= lo && d < hiN) {
            const int pos = atomicAdd(&cursor[d], 1);
            csr_src[pos] = esrc[e];
        }
    }
}

// ---------------- CSR aggregation: one wave per node, fp16 gather, 8x ILP ----------------
__global__ __launch_bounds__(256) void csr_aggregate(
    const int* __restrict__ row_ptr, const int* __restrict__ csr_src,
    const __half2* __restrict__ h2, const float2* __restrict__ as_,
    const float2* __restrict__ ad_, const float* __restrict__ bias,
    float* __restrict__ out, int N, int do_relu)
{
    const int lane = threadIdx.x & 63;
    const int node = (blockIdx.x * blockDim.x + threadIdx.x) >> 6;
    if (node >= N) return;

    const int start = row_ptr[node];
    const int end   = row_ptr[node + 1];
    const float2 ad = ad_[node];
    const bool hi = lane >= 32;

    float den0 = 0.f, den1 = 0.f;
    float accx = 0.f, accy = 0.f;

    for (int base = start; base < end; base += 64) {
        const int cnt = min(64, end - base);
        float ex0 = 0.f, ex1 = 0.f;
        int s = 0;
        if (lane < cnt) {
            s = csr_src[base + lane];
            const float2 as = as_[s];
            float e0 = as.x + ad.x; e0 = fmaxf(e0, 0.2f * e0);   // leaky relu
            float e1 = as.y + ad.y; e1 = fmaxf(e1, 0.2f * e1);
            ex0 = __expf(e0); ex1 = __expf(e1);
            den0 += ex0; den1 += ex1;
        }
        int j = 0;
        for (; j + 8 <= cnt; j += 8) {
            unsigned idx[8];
            float ej[8];
            float2 hv[8];
#pragma unroll
            for (int q = 0; q < 8; ++q) {
                idx[q] = (unsigned)(__builtin_amdgcn_readlane(s, j + q) * 64 + lane);
                ej[q] = hi ? rl_f(ex1, j + q) : rl_f(ex0, j + q);
            }
#pragma unroll
            for (int q = 0; q < 8; ++q)
                hv[q] = __half22float2(h2[idx[q]]);
#pragma unroll
            for (int q = 0; q < 8; ++q) {
                accx = fmaf(ej[q], hv[q].x, accx);
                accy = fmaf(ej[q], hv[q].y, accy);
            }
        }
        for (; j < cnt; ++j) {
            const unsigned idx = (unsigned)(__builtin_amdgcn_readlane(s, j) * 64 + lane);
            const float e = hi ? rl_f(ex1, j) : rl_f(ex0, j);
            const float2 hv = __half22float2(h2[idx]);
            accx = fmaf(e, hv.x, accx);
            accy = fmaf(e, hv.y, accy);
        }
    }

#pragma unroll
    for (int off = 32; off; off >>= 1) {
        den0 += __shfl_xor(den0, off, 64);
        den1 += __shfl_xor(den1, off, 64);
    }
    const float rd = 1.f / (hi ? den1 : den0);
    const float2 bv = ((const float2*)bias)[lane];
    float vx = fmaf(accx, rd, bv.x);
    float vy = fmaf(accy, rd, bv.y);
    if (do_relu) { vx = fmaxf(vx, 0.f); vy = fmaxf(vy, 0.f); }
    ((float2*)out)[(size_t)node * 64 + lane] = make_float2(vx, vy);
}

// ---------------- build rearranged decoder weight: Wuv[128][128] ----------------
__global__ void build_wuv(const float* __restrict__ lin1_w, float* __restrict__ Wuv)
{
    const int i = blockIdx.x * blockDim.x + threadIdx.x;
    if (i >= 128 * 128) return;
    const int k = i >> 7, j = i & 127;
    Wuv[i] = (j < 64) ? lin1_w[k * 64 + j] : lin1_w[(128 + k) * 64 + (j - 64)];
}

// ---------------- decoder: one wave per label edge (fp16 uv, 32-bit offsets) ----------------
__global__ __launch_bounds__(256) void decode_k(
    const int* __restrict__ eli, int L_, const __half* __restrict__ uv,
    const float* __restrict__ lin1_b, const float* __restrict__ lin2_w,
    const float* __restrict__ lin2_b, float* __restrict__ out)
{
    const int lane = threadIdx.x & 63;
    const int wstride = (gridDim.x * blockDim.x) >> 6;
    for (int wid = (blockIdx.x * blockDim.x + threadIdx.x) >> 6; wid < L_; wid += wstride) {
        const int a = eli[wid], b = eli[L_ + wid];
        const unsigned ia = (unsigned)(a * 128 + lane);
        const unsigned ib = (unsigned)(b * 128 + 64 + lane);
        float x = __half2float(uv[ia]) + __half2float(uv[ib]) + lin1_b[lane];
        x = x > 0.f ? x : 0.f;
        float p = x * lin2_w[lane];
#pragma unroll
        for (int off = 32; off; off >>= 1) p += __shfl_xor(p, off, 64);
        if (lane == 0) out[wid] = p + lin2_b[0];
    }
}

extern "C" void kernel_launch(void* const* d_in, const int* in_sizes, int n_in,
                              void* d_out, int out_size, void* d_ws, size_t ws_size,
                              hipStream_t stream)
{
    const float* x     = (const float*)d_in[0];
    const int*   ei    = (const int*)d_in[1];
    const int*   eli   = (const int*)d_in[2];
    const float* W1    = (const float*)d_in[3];
    const float* atts1 = (const float*)d_in[4];
    const float* attd1 = (const float*)d_in[5];
    const float* bias1 = (const float*)d_in[6];
    const float* W2    = (const float*)d_in[7];
    const float* atts2 = (const float*)d_in[8];
    const float* attd2 = (const float*)d_in[9];
    const float* bias2 = (const float*)d_in[10];
    const float* lin1w = (const float*)d_in[11];
    const float* lin1b = (const float*)d_in[12];
    const float* lin2w = (const float*)d_in[13];
    const float* lin2b = (const float*)d_in[14];
    float* out = (float*)d_out;

    const int N = in_sizes[0] / 128;
    const int E = in_sizes[1] / 2;
    const int L = in_sizes[2] / 2;

    float* ws   = (float*)d_ws;
    __half2* h16 = (__half2*)ws;                  // N*64 half2 = N*128 halfs
    float* x2z  = ws + (size_t)N * 64;            // N*128
    float* a_s  = x2z + (size_t)N * 128;          // N*2
    float* a_d  = a_s + (size_t)N * 2;            // N*2
    float* Wuv  = a_d + (size_t)N * 2;            // 128*128
    int* row_ptr = (int*)(Wuv + 128 * 128);       // N+1 (padded to N+4)
    int* counts  = row_ptr + (N + 4);             // N (16B-aligned)
    int* cursor  = counts + N;                    // N
    int* csr_src = cursor + N;                    // E+N
    int* blockSums = csr_src + (E + N);           // nb

    const int nBlocks256 = (N + 255) / 256;
    const int nb = (N + 1023) / 1024;
    const int npp = (N + 7) / 8;
    const int ntiles = (N + 63) / 64;
    const int gemmGrid = ntiles < 768 ? ntiles : 768;

    // ---- CSR build (once, reused by both layers) ----
    init_counts_k<<<nBlocks256, 256, 0, stream>>>(counts, N);
    hist_k<<<2048, 256, 0, stream>>>(ei + E, E, counts);
    scan_phase1<<<nb, 256, 0, stream>>>(counts, blockSums, N);
    scan_phase2<<<1, 256, 0, stream>>>(blockSums, nb, row_ptr, N);
    scan_phase3<<<nb, 256, 0, stream>>>(counts, blockSums, row_ptr, N);
    init_cursor_k<<<nBlocks256, 256, 0, stream>>>(row_ptr, cursor, csr_src, N);
    scatter_xcd_k<<<2048, 256, 0, stream>>>(ei, ei + E, E, cursor, csr_src, npp);

    for (int layer = 0; layer < 2; ++layer) {
        const float* xin  = (layer == 0) ? x : x2z;
        const float* W    = (layer == 0) ? W1 : W2;
        const float* as_w = (layer == 0) ? atts1 : atts2;
        const float* ad_w = (layer == 0) ? attd1 : attd2;
        const float* bs   = (layer == 0) ? bias1 : bias2;

        gemm_mfma<<<gemmGrid, 256, 0, stream>>>(xin, W, (_Float16*)h16, N, as_w, ad_w,
                                                (float2*)a_s, (float2*)a_d);
        csr_aggregate<<<(N + 3) / 4, 256, 0, stream>>>(row_ptr, csr_src, h16,
                                                       (const float2*)a_s, (const float2*)a_d,
                                                       bs, x2z, N, (layer == 0) ? 1 : 0);
    }

    build_wuv<<<64, 256, 0, stream>>>(lin1w, Wuv);
    gemm_mfma<<<gemmGrid, 256, 0, stream>>>(x2z, Wuv, (_Float16*)h16, N,
                                            nullptr, nullptr, nullptr, nullptr);
    decode_k<<<8192, 256, 0, stream>>>(eli, L, (const __half*)h16, lin1b, lin2w, lin2b, out);
}